// Round 6
// baseline (2087.763 us; speedup 1.0000x reference)
//
#include <hip/hip_runtime.h>

#define BB 4
#define TT 4096
#define CC 256

typedef __attribute__((ext_vector_type(8))) short short8;   // 8 x bf16 (4 VGPRs)
typedef __attribute__((ext_vector_type(4))) float f32x4;

#define SCALE 0.0625f  // C^-0.5 = 1/16

__device__ __forceinline__ float bf2f(unsigned short u) {
  union { unsigned int i; float f; } v; v.i = ((unsigned int)u) << 16; return v.f;
}
__device__ __forceinline__ unsigned short f2bf(float f) {
  union { float f; unsigned int i; } v; v.f = f;
  unsigned int x = v.i;
  unsigned int r = x + 0x7fffu + ((x >> 16) & 1u);  // RNE
  return (unsigned short)(r >> 16);
}

// ---------------- K0: input dtype detection ----------------
// f32 data viewed as u16: low halves random -> ~25% exponent-byte >= 0xC0.
// bf16 N(0,1): never. Robust either way.
__global__ __launch_bounds__(256) void detect_kernel(const unsigned short* __restrict__ xu,
                                                     int* __restrict__ flag) {
  __shared__ int part[4];
  int tid = threadIdx.x;
  int cnt = 0;
#pragma unroll
  for (int i = 0; i < 32; i++) {
    unsigned short u = xu[tid * 32 + i];
    int e = (u >> 7) & 0xff;
    cnt += (e >= 0xC0) ? 1 : 0;
  }
#pragma unroll
  for (int off = 32; off >= 1; off >>= 1) cnt += __shfl_xor(cnt, off);
  if ((tid & 63) == 0) part[tid >> 6] = cnt;
  __syncthreads();
  if (tid == 0) flag[0] = (part[0] + part[1] + part[2] + part[3] > 64) ? 1 : 0;
}

// ---------------- K0b: convert input array to bf16 ws copy ----------------
__global__ __launch_bounds__(256) void cvt_kernel(const void* __restrict__ src,
                                                  unsigned short* __restrict__ dst, int n,
                                                  const int* __restrict__ flag) {
  int i = blockIdx.x * 256 + threadIdx.x;
  if (i >= n) return;
  if (*flag)
    dst[i] = f2bf(((const float*)src)[i]);
  else
    dst[i] = ((const unsigned short*)src)[i];
}

// ---------------- K1: LayerNorm row stats (mu, rsqrt(var+eps)) ----------------
__global__ __launch_bounds__(256) void stats_kernel(const void* __restrict__ xv,
                                                    float2* __restrict__ stats,
                                                    const int* __restrict__ flagp) {
  int row = blockIdx.x * 4 + (threadIdx.x >> 6);
  int lane = threadIdx.x & 63;
  float f0, f1, f2, f3;
  if (*flagp) {
    const float* xr = (const float*)xv + (size_t)row * CC + lane * 4;
    float4 v = *(const float4*)xr;
    f0 = v.x; f1 = v.y; f2 = v.z; f3 = v.w;
  } else {
    const unsigned short* xr = (const unsigned short*)xv + (size_t)row * CC + lane * 4;
    uint2 v = *(const uint2*)xr;
    f0 = bf2f(v.x & 0xffffu); f1 = bf2f(v.x >> 16);
    f2 = bf2f(v.y & 0xffffu); f3 = bf2f(v.y >> 16);
  }
  float s = f0 + f1 + f2 + f3;
  float s2 = f0 * f0 + f1 * f1 + f2 * f2 + f3 * f3;
#pragma unroll
  for (int off = 32; off >= 1; off >>= 1) {
    s += __shfl_xor(s, off);
    s2 += __shfl_xor(s2, off);
  }
  if (lane == 0) {
    float mu = s * (1.0f / CC);
    float var = s2 * (1.0f / CC) - mu * mu;
    stats[row] = make_float2(mu, rsqrtf(var + 1e-5f));
  }
}

// ---------------- K2: fused LN + projection GEMM ----------------
// out[m,n] = sum_c ln(x)[row0+bz*TT+m,c] * W[n,c] + bias[n]
__global__ __launch_bounds__(256) void qkv_kernel(
    const void* __restrict__ xv, const float2* __restrict__ stats,
    const unsigned short* __restrict__ gmb, const unsigned short* __restrict__ btb,
    const unsigned short* __restrict__ Wb, const unsigned short* __restrict__ biasb,
    unsigned short* __restrict__ outp, int row0, const int* __restrict__ flagp) {
  constexpr int LD = 56;
  alignas(16) __shared__ unsigned short As[128 * LD];
  alignas(16) __shared__ unsigned short Bs[128 * LD];
  __shared__ float gf[CC], bfv[CC];
  int tid = threadIdx.x;
  int flag = *flagp;
  gf[tid] = bf2f(gmb[tid]);
  bfv[tid] = bf2f(btb[tid]);
  int row0e = row0 + blockIdx.z * TT;
  unsigned short* outpe = outp + (size_t)blockIdx.z * TT * CC;
  int m0 = blockIdx.x * 128, n0 = blockIdx.y * 128;
  int wid = tid >> 6, lane = tid & 63, qd = lane >> 4, l15 = lane & 15;
  int wm = wid >> 1, wn = wid & 1;
  f32x4 acc[4][4] = {};
  int srow = tid >> 2, sc8 = (tid & 3) * 8;
  float2 st0 = stats[row0e + m0 + srow];
  float2 st1 = stats[row0e + m0 + srow + 64];
  for (int kk = 0; kk < 8; kk++) {
    int k0 = kk * 32;
    __syncthreads();
#pragma unroll
    for (int rr = 0; rr < 2; rr++) {
      int r = srow + rr * 64;
      float2 st = rr ? st1 : st0;
      float v[8];
      if (flag) {
        const float* xr = (const float*)xv + (size_t)(row0e + m0 + r) * CC + k0 + sc8;
        float4 a = *(const float4*)xr;
        float4 b2 = *(const float4*)(xr + 4);
        v[0] = a.x; v[1] = a.y; v[2] = a.z; v[3] = a.w;
        v[4] = b2.x; v[5] = b2.y; v[6] = b2.z; v[7] = b2.w;
      } else {
        uint4 u = *(const uint4*)((const unsigned short*)xv +
                                  (size_t)(row0e + m0 + r) * CC + k0 + sc8);
        v[0] = bf2f(u.x & 0xffffu); v[1] = bf2f(u.x >> 16);
        v[2] = bf2f(u.y & 0xffffu); v[3] = bf2f(u.y >> 16);
        v[4] = bf2f(u.z & 0xffffu); v[5] = bf2f(u.z >> 16);
        v[6] = bf2f(u.w & 0xffffu); v[7] = bf2f(u.w >> 16);
      }
      union { unsigned short s[8]; uint4 u; } o;
#pragma unroll
      for (int j = 0; j < 8; j++)
        o.s[j] = f2bf((v[j] - st.x) * st.y * gf[k0 + sc8 + j] + bfv[k0 + sc8 + j]);
      *(uint4*)&As[r * LD + sc8] = o.u;
    }
    *(uint4*)&Bs[srow * LD + sc8] =
        *(const uint4*)(Wb + (size_t)(n0 + srow) * CC + k0 + sc8);
    *(uint4*)&Bs[(srow + 64) * LD + sc8] =
        *(const uint4*)(Wb + (size_t)(n0 + srow + 64) * CC + k0 + sc8);
    __syncthreads();
    short8 a[4], bfr[4];
#pragma unroll
    for (int mi = 0; mi < 4; mi++)
      a[mi] = *(const short8*)&As[(wm * 64 + mi * 16 + l15) * LD + qd * 8];
#pragma unroll
    for (int ni = 0; ni < 4; ni++)
      bfr[ni] = *(const short8*)&Bs[(wn * 64 + ni * 16 + l15) * LD + qd * 8];
#pragma unroll
    for (int mi = 0; mi < 4; mi++)
#pragma unroll
      for (int ni = 0; ni < 4; ni++)
        acc[mi][ni] =
            __builtin_amdgcn_mfma_f32_16x16x32_bf16(a[mi], bfr[ni], acc[mi][ni], 0, 0, 0);
  }
#pragma unroll
  for (int mi = 0; mi < 4; mi++)
#pragma unroll
    for (int ni = 0; ni < 4; ni++) {
      int n = n0 + wn * 64 + ni * 16 + l15;
      float bsv = bf2f(biasb[n]);
#pragma unroll
      for (int r = 0; r < 4; r++) {
        int m = m0 + wm * 64 + mi * 16 + qd * 4 + r;
        outpe[(size_t)m * CC + n] = f2bf(acc[mi][ni][r] + bsv);
      }
    }
}

// ---------------- K3: online (M_t, Z_t) over s ----------------
__global__ __launch_bounds__(256) void zsum_kernel(
    const unsigned short* __restrict__ q, const unsigned short* __restrict__ k,
    float* __restrict__ Mgp, float* __restrict__ zinvp) {
  constexpr int LD = 56;
  alignas(16) __shared__ unsigned short As[64 * LD];
  alignas(16) __shared__ unsigned short Bs[128 * LD];
  __shared__ float zm[2][64];
  __shared__ float zz[2][64];
  int tid = threadIdx.x;
  int t0 = blockIdx.x * 64;
  const unsigned short* qb = q + (size_t)blockIdx.y * TT * CC;
  const unsigned short* kb = k + (size_t)blockIdx.y * TT * CC;
  float* Mg = Mgp + (size_t)blockIdx.y * TT;
  float* zinv = zinvp + (size_t)blockIdx.y * TT;
  int wid = tid >> 6, lane = tid & 63, qd = lane >> 4, l15 = lane & 15;
  int wm = wid >> 1, wn = wid & 1;
  float mrun[2][4], zrun[2][4];
#pragma unroll
  for (int mi = 0; mi < 2; mi++)
#pragma unroll
    for (int r = 0; r < 4; r++) { mrun[mi][r] = -1e30f; zrun[mi][r] = 0.0f; }
  int srow = tid >> 2, sc8 = (tid & 3) * 8;
  for (int s0 = 0; s0 < TT; s0 += 128) {
    f32x4 acc[2][4] = {};
    for (int kk = 0; kk < 8; kk++) {
      int k0 = kk * 32;
      __syncthreads();
      *(uint4*)&As[srow * LD + sc8] =
          *(const uint4*)(qb + (size_t)(t0 + srow) * CC + k0 + sc8);
      *(uint4*)&Bs[srow * LD + sc8] =
          *(const uint4*)(kb + (size_t)(s0 + srow) * CC + k0 + sc8);
      *(uint4*)&Bs[(srow + 64) * LD + sc8] =
          *(const uint4*)(kb + (size_t)(s0 + srow + 64) * CC + k0 + sc8);
      __syncthreads();
      short8 a[2], bfr[4];
#pragma unroll
      for (int mi = 0; mi < 2; mi++)
        a[mi] = *(const short8*)&As[(wm * 32 + mi * 16 + l15) * LD + qd * 8];
#pragma unroll
      for (int ni = 0; ni < 4; ni++)
        bfr[ni] = *(const short8*)&Bs[(wn * 64 + ni * 16 + l15) * LD + qd * 8];
#pragma unroll
      for (int mi = 0; mi < 2; mi++)
#pragma unroll
        for (int ni = 0; ni < 4; ni++)
          acc[mi][ni] =
              __builtin_amdgcn_mfma_f32_16x16x32_bf16(a[mi], bfr[ni], acc[mi][ni], 0, 0, 0);
    }
#pragma unroll
    for (int mi = 0; mi < 2; mi++)
#pragma unroll
      for (int r = 0; r < 4; r++) {
        float v0 = acc[mi][0][r] * SCALE, v1 = acc[mi][1][r] * SCALE;
        float v2 = acc[mi][2][r] * SCALE, v3 = acc[mi][3][r] * SCALE;
        float cm = fmaxf(fmaxf(v0, v1), fmaxf(v2, v3));
        float mn = fmaxf(mrun[mi][r], cm);
        float e = __expf(v0 - mn) + __expf(v1 - mn) + __expf(v2 - mn) + __expf(v3 - mn);
        zrun[mi][r] = zrun[mi][r] * __expf(mrun[mi][r] - mn) + e;
        mrun[mi][r] = mn;
      }
  }
#pragma unroll
  for (int mi = 0; mi < 2; mi++)
#pragma unroll
    for (int r = 0; r < 4; r++) {
      float m = mrun[mi][r], z = zrun[mi][r];
#pragma unroll
      for (int mask = 1; mask <= 8; mask <<= 1) {
        float mo = __shfl_xor(m, mask);
        float zo = __shfl_xor(z, mask);
        float mn = fmaxf(m, mo);
        z = z * __expf(m - mn) + zo * __expf(mo - mn);
        m = mn;
      }
      mrun[mi][r] = m; zrun[mi][r] = z;
    }
  if (l15 == 0) {
#pragma unroll
    for (int mi = 0; mi < 2; mi++)
#pragma unroll
      for (int r = 0; r < 4; r++) {
        int tl = wm * 32 + mi * 16 + qd * 4 + r;
        zm[wn][tl] = mrun[mi][r];
        zz[wn][tl] = zrun[mi][r];
      }
  }
  __syncthreads();
  if (tid < 64) {
    float m0 = zm[0][tid], z0 = zz[0][tid];
    float m1 = zm[1][tid], z1 = zz[1][tid];
    float M = fmaxf(m0, m1);
    float Z = z0 * __expf(m0 - M) + z1 * __expf(m1 - M);
    Mg[t0 + tid] = M;
    zinv[t0 + tid] = 1.0f / Z;
  }
}

// ---------------- K4: MFMA S-phase + vector PV; f32 OUTPUT ----------------
__global__ __launch_bounds__(256) void attn2_kernel(
    const unsigned short* __restrict__ q, const unsigned short* __restrict__ k,
    const unsigned short* __restrict__ v, const float* __restrict__ Mgp,
    const float* __restrict__ zinvp, const void* __restrict__ xv,
    float* __restrict__ out, int row0, const int* __restrict__ flagp) {
  constexpr int LD = 56, PS = 65;
  alignas(16) __shared__ unsigned short As[128 * LD];
  alignas(16) __shared__ unsigned short Bs[64 * LD];
  __shared__ float Ps[128 * PS];
  int tid = threadIdx.x;
  int flag = *flagp;
  int s0 = blockIdx.x * 64;
  int row0e = row0 + blockIdx.y * TT;
  const unsigned short* qb = q + (size_t)blockIdx.y * TT * CC;
  const unsigned short* kb = k + (size_t)blockIdx.y * TT * CC;
  const unsigned short* vb = v + (size_t)blockIdx.y * TT * CC;
  const float* Mg = Mgp + (size_t)blockIdx.y * TT;
  const float* zinv = zinvp + (size_t)blockIdx.y * TT;
  int wid = tid >> 6, lane = tid & 63, qd = lane >> 4, l15 = lane & 15;
  int tw = wid >> 1, sw = wid & 1;
  int sown = tid & 63;
  int cw = tid >> 6;
  float oacc[64];
#pragma unroll
  for (int i = 0; i < 64; i++) oacc[i] = 0.0f;
  int srow = tid >> 2, sc8 = (tid & 3) * 8;
  for (int tc = 0; tc < TT; tc += 128) {
    f32x4 sacc[4][2] = {};
    for (int kk = 0; kk < 8; kk++) {
      int k0 = kk * 32;
      __syncthreads();
      *(uint4*)&As[srow * LD + sc8] =
          *(const uint4*)(qb + (size_t)(tc + srow) * CC + k0 + sc8);
      *(uint4*)&As[(srow + 64) * LD + sc8] =
          *(const uint4*)(qb + (size_t)(tc + srow + 64) * CC + k0 + sc8);
      *(uint4*)&Bs[srow * LD + sc8] =
          *(const uint4*)(kb + (size_t)(s0 + srow) * CC + k0 + sc8);
      __syncthreads();
      short8 a[4], bfr[2];
#pragma unroll
      for (int mi = 0; mi < 4; mi++)
        a[mi] = *(const short8*)&As[(tw * 64 + mi * 16 + l15) * LD + qd * 8];
#pragma unroll
      for (int ni = 0; ni < 2; ni++)
        bfr[ni] = *(const short8*)&Bs[(sw * 32 + ni * 16 + l15) * LD + qd * 8];
#pragma unroll
      for (int mi = 0; mi < 4; mi++)
#pragma unroll
        for (int ni = 0; ni < 2; ni++)
          sacc[mi][ni] =
              __builtin_amdgcn_mfma_f32_16x16x32_bf16(a[mi], bfr[ni], sacc[mi][ni], 0, 0, 0);
    }
#pragma unroll
    for (int mi = 0; mi < 4; mi++) {
      int tb = tw * 64 + mi * 16 + qd * 4;
      f32x4 M4 = *(const f32x4*)&Mg[tc + tb];
      f32x4 Z4 = *(const f32x4*)&zinv[tc + tb];
#pragma unroll
      for (int ni = 0; ni < 2; ni++) {
        int s_loc = sw * 32 + ni * 16 + l15;
#pragma unroll
        for (int r = 0; r < 4; r++)
          Ps[(tb + r) * PS + s_loc] = __expf(sacc[mi][ni][r] * SCALE - M4[r]) * Z4[r];
      }
    }
    __syncthreads();
    const unsigned short* vrow = vb + (size_t)tc * CC + cw * 64;
    for (int t = 0; t < 128; t++) {
      float p = Ps[t * PS + sown];
      const uint2* vp = (const uint2*)(vrow + (size_t)t * CC);
#pragma unroll
      for (int ci = 0; ci < 16; ci++) {
        uint2 pk = vp[ci];
        oacc[ci * 4 + 0] += p * bf2f(pk.x & 0xffffu);
        oacc[ci * 4 + 1] += p * bf2f(pk.x >> 16);
        oacc[ci * 4 + 2] += p * bf2f(pk.y & 0xffffu);
        oacc[ci * 4 + 3] += p * bf2f(pk.y >> 16);
      }
    }
  }
  // epilogue: out(f32) = oacc + x
#pragma unroll
  for (int ci = 0; ci < 64; ci += 4) {
    size_t idx = ((size_t)(row0e + s0 + sown)) * CC + cw * 64 + ci;
    float4 xr;
    if (flag) {
      xr = *(const float4*)((const float*)xv + idx);
    } else {
      uint2 u = *(const uint2*)((const unsigned short*)xv + idx);
      xr.x = bf2f(u.x & 0xffffu); xr.y = bf2f(u.x >> 16);
      xr.z = bf2f(u.y & 0xffffu); xr.w = bf2f(u.y >> 16);
    }
    float4 o;
    o.x = oacc[ci + 0] + xr.x;
    o.y = oacc[ci + 1] + xr.y;
    o.z = oacc[ci + 2] + xr.z;
    o.w = oacc[ci + 3] + xr.w;
    *(float4*)&out[idx] = o;
  }
}

extern "C" void kernel_launch(void* const* d_in, const int* in_sizes, int n_in,
                              void* d_out, int out_size, void* d_ws, size_t ws_size,
                              hipStream_t stream) {
  const void* x = d_in[0];
  const void* gamma = d_in[1];
  const void* beta = d_in[2];
  const void* Wq = d_in[3];
  const void* bq = d_in[4];
  const void* Wk = d_in[5];
  const void* bk = d_in[6];
  const void* Wv = d_in[7];
  const void* bv = d_in[8];
  float* out = (float*)d_out;  // reference output dtype: float32

  char* ws = (char*)d_ws;
  int* flag = (int*)(ws + 0);                                // 4 B
  float2* stats = (float2*)(ws + 1024);                      // 128 KiB (all rows)
  unsigned short* gmb = (unsigned short*)(ws + 132096);      // 512 B each
  unsigned short* btb = (unsigned short*)(ws + 132608);
  unsigned short* bqb = (unsigned short*)(ws + 133120);
  unsigned short* bkb = (unsigned short*)(ws + 133632);
  unsigned short* bvb = (unsigned short*)(ws + 134144);
  unsigned short* Wqb = (unsigned short*)(ws + 135168);      // 128 KiB each
  unsigned short* Wkb = (unsigned short*)(ws + 266240);
  unsigned short* Wvb = (unsigned short*)(ws + 397312);
  float* Mg = (float*)(ws + 528384);                         // 64 KiB (4 batches)
  float* zinv = (float*)(ws + 593920);                       // 64 KiB
  unsigned short* qb = (unsigned short*)(ws + 1048576);      // up to 8 MiB
  // full mode: q/k/v are 8 MiB each (all batches); per-batch: 2 MiB each
  const int full = (ws_size >= 26214400u);
  size_t qkv_bytes = full ? 8388608u : 2097152u;
  unsigned short* kb = (unsigned short*)((char*)qb + qkv_bytes);
  unsigned short* vb = (unsigned short*)((char*)kb + qkv_bytes);

  detect_kernel<<<dim3(1), dim3(256), 0, stream>>>((const unsigned short*)x, flag);
  cvt_kernel<<<dim3(256), dim3(256), 0, stream>>>(Wq, Wqb, CC * CC, flag);
  cvt_kernel<<<dim3(256), dim3(256), 0, stream>>>(Wk, Wkb, CC * CC, flag);
  cvt_kernel<<<dim3(256), dim3(256), 0, stream>>>(Wv, Wvb, CC * CC, flag);
  cvt_kernel<<<dim3(1), dim3(256), 0, stream>>>(bq, bqb, CC, flag);
  cvt_kernel<<<dim3(1), dim3(256), 0, stream>>>(bk, bkb, CC, flag);
  cvt_kernel<<<dim3(1), dim3(256), 0, stream>>>(bv, bvb, CC, flag);
  cvt_kernel<<<dim3(1), dim3(256), 0, stream>>>(gamma, gmb, CC, flag);
  cvt_kernel<<<dim3(1), dim3(256), 0, stream>>>(beta, btb, CC, flag);
  stats_kernel<<<dim3(BB * TT / 4), dim3(256), 0, stream>>>(x, stats, flag);

  if (full) {
    qkv_kernel<<<dim3(32, 2, BB), dim3(256), 0, stream>>>(x, stats, gmb, btb, Wqb, bqb,
                                                          qb, 0, flag);
    qkv_kernel<<<dim3(32, 2, BB), dim3(256), 0, stream>>>(x, stats, gmb, btb, Wkb, bkb,
                                                          kb, 0, flag);
    qkv_kernel<<<dim3(32, 2, BB), dim3(256), 0, stream>>>(x, stats, gmb, btb, Wvb, bvb,
                                                          vb, 0, flag);
    zsum_kernel<<<dim3(64, BB), dim3(256), 0, stream>>>(qb, kb, Mg, zinv);
    attn2_kernel<<<dim3(64, BB), dim3(256), 0, stream>>>(qb, kb, vb, Mg, zinv, x, out, 0,
                                                         flag);
  } else {
    for (int b = 0; b < BB; b++) {
      int row0 = b * TT;
      qkv_kernel<<<dim3(32, 2, 1), dim3(256), 0, stream>>>(x, stats, gmb, btb, Wqb, bqb,
                                                           qb, row0, flag);
      qkv_kernel<<<dim3(32, 2, 1), dim3(256), 0, stream>>>(x, stats, gmb, btb, Wkb, bkb,
                                                           kb, row0, flag);
      qkv_kernel<<<dim3(32, 2, 1), dim3(256), 0, stream>>>(x, stats, gmb, btb, Wvb, bvb,
                                                           vb, row0, flag);
      zsum_kernel<<<dim3(64, 1), dim3(256), 0, stream>>>(qb, kb, Mg, zinv);
      attn2_kernel<<<dim3(64, 1), dim3(256), 0, stream>>>(qb, kb, vb, Mg, zinv, x, out,
                                                          row0, flag);
    }
  }
}

// Round 7
// 615.600 us; speedup vs baseline: 3.3914x; 3.3914x over previous
//
#include <hip/hip_runtime.h>

#define BB 4
#define TT 4096
#define CC 256

typedef __attribute__((ext_vector_type(8))) short short8;   // 8 x bf16 (4 VGPRs)
typedef __attribute__((ext_vector_type(4))) float f32x4;

#define SCALE 0.0625f  // C^-0.5 = 1/16

__device__ __forceinline__ float bf2f(unsigned short u) {
  union { unsigned int i; float f; } v; v.i = ((unsigned int)u) << 16; return v.f;
}
__device__ __forceinline__ unsigned short f2bf(float f) {
  union { float f; unsigned int i; } v; v.f = f;
  unsigned int x = v.i;
  unsigned int r = x + 0x7fffu + ((x >> 16) & 1u);  // RNE
  return (unsigned short)(r >> 16);
}

// ---------------- K0: input dtype detection ----------------
__global__ __launch_bounds__(256) void detect_kernel(const unsigned short* __restrict__ xu,
                                                     int* __restrict__ flag) {
  __shared__ int part[4];
  int tid = threadIdx.x;
  int cnt = 0;
#pragma unroll
  for (int i = 0; i < 32; i++) {
    unsigned short u = xu[tid * 32 + i];
    int e = (u >> 7) & 0xff;
    cnt += (e >= 0xC0) ? 1 : 0;
  }
#pragma unroll
  for (int off = 32; off >= 1; off >>= 1) cnt += __shfl_xor(cnt, off);
  if ((tid & 63) == 0) part[tid >> 6] = cnt;
  __syncthreads();
  if (tid == 0) flag[0] = (part[0] + part[1] + part[2] + part[3] > 64) ? 1 : 0;
}

// ---------------- K0b: convert input array to bf16 ws copy ----------------
__global__ __launch_bounds__(256) void cvt_kernel(const void* __restrict__ src,
                                                  unsigned short* __restrict__ dst, int n,
                                                  const int* __restrict__ flag) {
  int i = blockIdx.x * 256 + threadIdx.x;
  if (i >= n) return;
  if (*flag)
    dst[i] = f2bf(((const float*)src)[i]);
  else
    dst[i] = ((const unsigned short*)src)[i];
}

// ---------------- K1: LayerNorm row stats (mu, rsqrt(var+eps)) ----------------
__global__ __launch_bounds__(256) void stats_kernel(const void* __restrict__ xv,
                                                    float2* __restrict__ stats,
                                                    const int* __restrict__ flagp) {
  int row = blockIdx.x * 4 + (threadIdx.x >> 6);
  int lane = threadIdx.x & 63;
  float f0, f1, f2, f3;
  if (*flagp) {
    const float* xr = (const float*)xv + (size_t)row * CC + lane * 4;
    float4 v = *(const float4*)xr;
    f0 = v.x; f1 = v.y; f2 = v.z; f3 = v.w;
  } else {
    const unsigned short* xr = (const unsigned short*)xv + (size_t)row * CC + lane * 4;
    uint2 v = *(const uint2*)xr;
    f0 = bf2f(v.x & 0xffffu); f1 = bf2f(v.x >> 16);
    f2 = bf2f(v.y & 0xffffu); f3 = bf2f(v.y >> 16);
  }
  float s = f0 + f1 + f2 + f3;
  float s2 = f0 * f0 + f1 * f1 + f2 * f2 + f3 * f3;
#pragma unroll
  for (int off = 32; off >= 1; off >>= 1) {
    s += __shfl_xor(s, off);
    s2 += __shfl_xor(s2, off);
  }
  if (lane == 0) {
    float mu = s * (1.0f / CC);
    float var = s2 * (1.0f / CC) - mu * mu;
    stats[row] = make_float2(mu, rsqrtf(var + 1e-5f));
  }
}

// ---------------- K2: fused LN + projection GEMM ----------------
// out[m,n] = sum_c ln(x)[row0+bz*TT+m,c] * W[n,c] + bias[n]
// transposed==0: outpe[m*CC+n]; ==1: outpe[n*TT+m]  (V^T layout per batch)
__global__ __launch_bounds__(256) void qkv_kernel(
    const void* __restrict__ xv, const float2* __restrict__ stats,
    const unsigned short* __restrict__ gmb, const unsigned short* __restrict__ btb,
    const unsigned short* __restrict__ Wb, const unsigned short* __restrict__ biasb,
    unsigned short* __restrict__ outp, int row0, int transposed,
    const int* __restrict__ flagp) {
  constexpr int LD = 56;
  alignas(16) __shared__ unsigned short As[128 * LD];
  alignas(16) __shared__ unsigned short Bs[128 * LD];
  __shared__ float gf[CC], bfv[CC];
  int tid = threadIdx.x;
  int flag = *flagp;
  gf[tid] = bf2f(gmb[tid]);
  bfv[tid] = bf2f(btb[tid]);
  int row0e = row0 + blockIdx.z * TT;
  unsigned short* outpe = outp + (size_t)blockIdx.z * TT * CC;
  int m0 = blockIdx.x * 128, n0 = blockIdx.y * 128;
  int wid = tid >> 6, lane = tid & 63, qd = lane >> 4, l15 = lane & 15;
  int wm = wid >> 1, wn = wid & 1;
  f32x4 acc[4][4] = {};
  int srow = tid >> 2, sc8 = (tid & 3) * 8;
  float2 st0 = stats[row0e + m0 + srow];
  float2 st1 = stats[row0e + m0 + srow + 64];
  for (int kk = 0; kk < 8; kk++) {
    int k0 = kk * 32;
    __syncthreads();
#pragma unroll
    for (int rr = 0; rr < 2; rr++) {
      int r = srow + rr * 64;
      float2 st = rr ? st1 : st0;
      float v[8];
      if (flag) {
        const float* xr = (const float*)xv + (size_t)(row0e + m0 + r) * CC + k0 + sc8;
        float4 a = *(const float4*)xr;
        float4 b2 = *(const float4*)(xr + 4);
        v[0] = a.x; v[1] = a.y; v[2] = a.z; v[3] = a.w;
        v[4] = b2.x; v[5] = b2.y; v[6] = b2.z; v[7] = b2.w;
      } else {
        uint4 u = *(const uint4*)((const unsigned short*)xv +
                                  (size_t)(row0e + m0 + r) * CC + k0 + sc8);
        v[0] = bf2f(u.x & 0xffffu); v[1] = bf2f(u.x >> 16);
        v[2] = bf2f(u.y & 0xffffu); v[3] = bf2f(u.y >> 16);
        v[4] = bf2f(u.z & 0xffffu); v[5] = bf2f(u.z >> 16);
        v[6] = bf2f(u.w & 0xffffu); v[7] = bf2f(u.w >> 16);
      }
      union { unsigned short s[8]; uint4 u; } o;
#pragma unroll
      for (int j = 0; j < 8; j++)
        o.s[j] = f2bf((v[j] - st.x) * st.y * gf[k0 + sc8 + j] + bfv[k0 + sc8 + j]);
      *(uint4*)&As[r * LD + sc8] = o.u;
    }
    *(uint4*)&Bs[srow * LD + sc8] =
        *(const uint4*)(Wb + (size_t)(n0 + srow) * CC + k0 + sc8);
    *(uint4*)&Bs[(srow + 64) * LD + sc8] =
        *(const uint4*)(Wb + (size_t)(n0 + srow + 64) * CC + k0 + sc8);
    __syncthreads();
    short8 a[4], bfr[4];
#pragma unroll
    for (int mi = 0; mi < 4; mi++)
      a[mi] = *(const short8*)&As[(wm * 64 + mi * 16 + l15) * LD + qd * 8];
#pragma unroll
    for (int ni = 0; ni < 4; ni++)
      bfr[ni] = *(const short8*)&Bs[(wn * 64 + ni * 16 + l15) * LD + qd * 8];
#pragma unroll
    for (int mi = 0; mi < 4; mi++)
#pragma unroll
      for (int ni = 0; ni < 4; ni++)
        acc[mi][ni] =
            __builtin_amdgcn_mfma_f32_16x16x32_bf16(a[mi], bfr[ni], acc[mi][ni], 0, 0, 0);
  }
#pragma unroll
  for (int mi = 0; mi < 4; mi++)
#pragma unroll
    for (int ni = 0; ni < 4; ni++) {
      int n = n0 + wn * 64 + ni * 16 + l15;
      float bsv = bf2f(biasb[n]);
#pragma unroll
      for (int r = 0; r < 4; r++) {
        int m = m0 + wm * 64 + mi * 16 + qd * 4 + r;
        unsigned short val = f2bf(acc[mi][ni][r] + bsv);
        if (transposed)
          outpe[(size_t)n * TT + m] = val;
        else
          outpe[(size_t)m * CC + n] = val;
      }
    }
}

// ---------------- K3: online (M_t, Z_t) over s ----------------
__global__ __launch_bounds__(256) void zsum_kernel(
    const unsigned short* __restrict__ q, const unsigned short* __restrict__ k,
    float* __restrict__ Mgp, float* __restrict__ zinvp) {
  constexpr int LD = 56;
  alignas(16) __shared__ unsigned short As[64 * LD];
  alignas(16) __shared__ unsigned short Bs[128 * LD];
  __shared__ float zm[2][64];
  __shared__ float zz[2][64];
  int tid = threadIdx.x;
  int t0 = blockIdx.x * 64;
  const unsigned short* qb = q + (size_t)blockIdx.y * TT * CC;
  const unsigned short* kb = k + (size_t)blockIdx.y * TT * CC;
  float* Mg = Mgp + (size_t)blockIdx.y * TT;
  float* zinv = zinvp + (size_t)blockIdx.y * TT;
  int wid = tid >> 6, lane = tid & 63, qd = lane >> 4, l15 = lane & 15;
  int wm = wid >> 1, wn = wid & 1;
  float mrun[2][4], zrun[2][4];
#pragma unroll
  for (int mi = 0; mi < 2; mi++)
#pragma unroll
    for (int r = 0; r < 4; r++) { mrun[mi][r] = -1e30f; zrun[mi][r] = 0.0f; }
  int srow = tid >> 2, sc8 = (tid & 3) * 8;
  for (int s0 = 0; s0 < TT; s0 += 128) {
    f32x4 acc[2][4] = {};
    for (int kk = 0; kk < 8; kk++) {
      int k0 = kk * 32;
      __syncthreads();
      *(uint4*)&As[srow * LD + sc8] =
          *(const uint4*)(qb + (size_t)(t0 + srow) * CC + k0 + sc8);
      *(uint4*)&Bs[srow * LD + sc8] =
          *(const uint4*)(kb + (size_t)(s0 + srow) * CC + k0 + sc8);
      *(uint4*)&Bs[(srow + 64) * LD + sc8] =
          *(const uint4*)(kb + (size_t)(s0 + srow + 64) * CC + k0 + sc8);
      __syncthreads();
      short8 a[2], bfr[4];
#pragma unroll
      for (int mi = 0; mi < 2; mi++)
        a[mi] = *(const short8*)&As[(wm * 32 + mi * 16 + l15) * LD + qd * 8];
#pragma unroll
      for (int ni = 0; ni < 4; ni++)
        bfr[ni] = *(const short8*)&Bs[(wn * 64 + ni * 16 + l15) * LD + qd * 8];
#pragma unroll
      for (int mi = 0; mi < 2; mi++)
#pragma unroll
        for (int ni = 0; ni < 4; ni++)
          acc[mi][ni] =
              __builtin_amdgcn_mfma_f32_16x16x32_bf16(a[mi], bfr[ni], acc[mi][ni], 0, 0, 0);
    }
#pragma unroll
    for (int mi = 0; mi < 2; mi++)
#pragma unroll
      for (int r = 0; r < 4; r++) {
        float v0 = acc[mi][0][r] * SCALE, v1 = acc[mi][1][r] * SCALE;
        float v2 = acc[mi][2][r] * SCALE, v3 = acc[mi][3][r] * SCALE;
        float cm = fmaxf(fmaxf(v0, v1), fmaxf(v2, v3));
        float mn = fmaxf(mrun[mi][r], cm);
        float e = __expf(v0 - mn) + __expf(v1 - mn) + __expf(v2 - mn) + __expf(v3 - mn);
        zrun[mi][r] = zrun[mi][r] * __expf(mrun[mi][r] - mn) + e;
        mrun[mi][r] = mn;
      }
  }
#pragma unroll
  for (int mi = 0; mi < 2; mi++)
#pragma unroll
    for (int r = 0; r < 4; r++) {
      float m = mrun[mi][r], z = zrun[mi][r];
#pragma unroll
      for (int mask = 1; mask <= 8; mask <<= 1) {
        float mo = __shfl_xor(m, mask);
        float zo = __shfl_xor(z, mask);
        float mn = fmaxf(m, mo);
        z = z * __expf(m - mn) + zo * __expf(mo - mn);
        m = mn;
      }
      mrun[mi][r] = m; zrun[mi][r] = z;
    }
  if (l15 == 0) {
#pragma unroll
    for (int mi = 0; mi < 2; mi++)
#pragma unroll
      for (int r = 0; r < 4; r++) {
        int tl = wm * 32 + mi * 16 + qd * 4 + r;
        zm[wn][tl] = mrun[mi][r];
        zz[wn][tl] = zrun[mi][r];
      }
  }
  __syncthreads();
  if (tid < 64) {
    float m0 = zm[0][tid], z0 = zz[0][tid];
    float m1 = zm[1][tid], z1 = zz[1][tid];
    float M = fmaxf(m0, m1);
    float Z = z0 * __expf(m0 - M) + z1 * __expf(m1 - M);
    Mg[t0 + tid] = M;
    zinv[t0 + tid] = 1.0f / Z;
  }
}

// ---------------- K4: MFMA S-phase + MFMA PV phase; f32 OUTPUT ----------------
// out[s,c] = x[s,c] + sum_t P[t,s]*v[t,c].  P^T staged in LDS (bf16), V^T in ws.
__global__ __launch_bounds__(256) void attn_kernel(
    const unsigned short* __restrict__ q, const unsigned short* __restrict__ k,
    const unsigned short* __restrict__ vt, const float* __restrict__ Mgp,
    const float* __restrict__ zinvp, const void* __restrict__ xv,
    float* __restrict__ out, int row0, const int* __restrict__ flagp) {
  // LP=144: row stride 288 B = 32 B mod 128 -> consecutive rows spread banks
  constexpr int LD = 56, LP = 144;
  alignas(16) __shared__ unsigned short As[128 * LD];  // q t-chunk (128 x 32)
  alignas(16) __shared__ unsigned short Bs[64 * LD];   // k s-tile (64 x 32)
  alignas(16) __shared__ unsigned short Pt[64 * LP];   // P^T [s][t], t-chunk 128
  int tid = threadIdx.x;
  int flag = *flagp;
  int s0 = blockIdx.x * 64;
  int row0e = row0 + blockIdx.y * TT;
  const unsigned short* qb = q + (size_t)blockIdx.y * TT * CC;
  const unsigned short* kb = k + (size_t)blockIdx.y * TT * CC;
  const unsigned short* vtb = vt + (size_t)blockIdx.y * TT * CC;  // [c][t]
  const float* Mg = Mgp + (size_t)blockIdx.y * TT;
  const float* zinv = zinvp + (size_t)blockIdx.y * TT;
  int wid = tid >> 6, lane = tid & 63, qd = lane >> 4, l15 = lane & 15;
  int tw = wid >> 1, sw = wid & 1;  // S-phase: t tw*64+[0,64), s sw*32+[0,32)
  int ow = wid >> 1, oc = wid & 1;  // PV: s ow*32+[0,32), c oc*128+[0,128)
  f32x4 oacc[2][8] = {};
  int srow = tid >> 2, sc8 = (tid & 3) * 8;
  for (int tc = 0; tc < TT; tc += 128) {
    f32x4 sacc[4][2] = {};
    for (int kk = 0; kk < 8; kk++) {
      int k0 = kk * 32;
      __syncthreads();
      *(uint4*)&As[srow * LD + sc8] =
          *(const uint4*)(qb + (size_t)(tc + srow) * CC + k0 + sc8);
      *(uint4*)&As[(srow + 64) * LD + sc8] =
          *(const uint4*)(qb + (size_t)(tc + srow + 64) * CC + k0 + sc8);
      *(uint4*)&Bs[srow * LD + sc8] =
          *(const uint4*)(kb + (size_t)(s0 + srow) * CC + k0 + sc8);
      __syncthreads();
      short8 a[4], bfr[2];
#pragma unroll
      for (int mi = 0; mi < 4; mi++)
        a[mi] = *(const short8*)&As[(tw * 64 + mi * 16 + l15) * LD + qd * 8];
#pragma unroll
      for (int ni = 0; ni < 2; ni++)
        bfr[ni] = *(const short8*)&Bs[(sw * 32 + ni * 16 + l15) * LD + qd * 8];
#pragma unroll
      for (int mi = 0; mi < 4; mi++)
#pragma unroll
        for (int ni = 0; ni < 2; ni++)
          sacc[mi][ni] =
              __builtin_amdgcn_mfma_f32_16x16x32_bf16(a[mi], bfr[ni], sacc[mi][ni], 0, 0, 0);
    }
    // S -> P = exp(S*scale - M_t)*zinv_t, write transposed (bf16) to Pt[s][t]
#pragma unroll
    for (int mi = 0; mi < 4; mi++) {
      int tb = tw * 64 + mi * 16 + qd * 4;
      f32x4 M4 = *(const f32x4*)&Mg[tc + tb];
      f32x4 Z4 = *(const f32x4*)&zinv[tc + tb];
#pragma unroll
      for (int ni = 0; ni < 2; ni++) {
        int s_loc = sw * 32 + ni * 16 + l15;
        float p0 = __expf(sacc[mi][ni][0] * SCALE - M4[0]) * Z4[0];
        float p1 = __expf(sacc[mi][ni][1] * SCALE - M4[1]) * Z4[1];
        float p2 = __expf(sacc[mi][ni][2] * SCALE - M4[2]) * Z4[2];
        float p3 = __expf(sacc[mi][ni][3] * SCALE - M4[3]) * Z4[3];
        uint2 pk;
        pk.x = (unsigned int)f2bf(p0) | ((unsigned int)f2bf(p1) << 16);
        pk.y = (unsigned int)f2bf(p2) | ((unsigned int)f2bf(p3) << 16);
        *(uint2*)&Pt[s_loc * LP + tb] = pk;
      }
    }
    __syncthreads();
    // PV: oacc[s,c] += P^T[s,t] * Vt[c,t]  (both operands in [row][k] layout)
#pragma unroll
    for (int kt = 0; kt < 4; kt++) {
      short8 a2[2], b2[8];
#pragma unroll
      for (int mi = 0; mi < 2; mi++)
        a2[mi] = *(const short8*)&Pt[(ow * 32 + mi * 16 + l15) * LP + kt * 32 + qd * 8];
#pragma unroll
      for (int ni = 0; ni < 8; ni++) {
        int c = oc * 128 + ni * 16 + l15;
        b2[ni] = *(const short8*)(vtb + (size_t)c * TT + tc + kt * 32 + qd * 8);
      }
#pragma unroll
      for (int mi = 0; mi < 2; mi++)
#pragma unroll
        for (int ni = 0; ni < 8; ni++)
          oacc[mi][ni] =
              __builtin_amdgcn_mfma_f32_16x16x32_bf16(a2[mi], b2[ni], oacc[mi][ni], 0, 0, 0);
    }
  }
  // epilogue: out(f32) = oacc + x
#pragma unroll
  for (int mi = 0; mi < 2; mi++)
#pragma unroll
    for (int ni = 0; ni < 8; ni++)
#pragma unroll
      for (int r = 0; r < 4; r++) {
        int s = s0 + ow * 32 + mi * 16 + qd * 4 + r;
        int c = oc * 128 + ni * 16 + l15;
        size_t idx = ((size_t)(row0e + s)) * CC + c;
        float xr = flag ? ((const float*)xv)[idx] : bf2f(((const unsigned short*)xv)[idx]);
        out[idx] = oacc[mi][ni][r] + xr;
      }
}

extern "C" void kernel_launch(void* const* d_in, const int* in_sizes, int n_in,
                              void* d_out, int out_size, void* d_ws, size_t ws_size,
                              hipStream_t stream) {
  const void* x = d_in[0];
  const void* gamma = d_in[1];
  const void* beta = d_in[2];
  const void* Wq = d_in[3];
  const void* bq = d_in[4];
  const void* Wk = d_in[5];
  const void* bk = d_in[6];
  const void* Wv = d_in[7];
  const void* bv = d_in[8];
  float* out = (float*)d_out;  // reference output dtype: float32

  char* ws = (char*)d_ws;
  int* flag = (int*)(ws + 0);                                // 4 B
  float2* stats = (float2*)(ws + 1024);                      // 128 KiB (all rows)
  unsigned short* gmb = (unsigned short*)(ws + 132096);      // 512 B each
  unsigned short* btb = (unsigned short*)(ws + 132608);
  unsigned short* bqb = (unsigned short*)(ws + 133120);
  unsigned short* bkb = (unsigned short*)(ws + 133632);
  unsigned short* bvb = (unsigned short*)(ws + 134144);
  unsigned short* Wqb = (unsigned short*)(ws + 135168);      // 128 KiB each
  unsigned short* Wkb = (unsigned short*)(ws + 266240);
  unsigned short* Wvb = (unsigned short*)(ws + 397312);
  float* Mg = (float*)(ws + 528384);                         // 64 KiB (4 batches)
  float* zinv = (float*)(ws + 593920);                       // 64 KiB
  unsigned short* qb = (unsigned short*)(ws + 1048576);
  const int full = (ws_size >= 26214400u);
  size_t qkv_bytes = full ? 8388608u : 2097152u;
  unsigned short* kb = (unsigned short*)((char*)qb + qkv_bytes);
  unsigned short* vtb = (unsigned short*)((char*)kb + qkv_bytes);  // V^T [b][c][t]

  detect_kernel<<<dim3(1), dim3(256), 0, stream>>>((const unsigned short*)x, flag);
  cvt_kernel<<<dim3(256), dim3(256), 0, stream>>>(Wq, Wqb, CC * CC, flag);
  cvt_kernel<<<dim3(256), dim3(256), 0, stream>>>(Wk, Wkb, CC * CC, flag);
  cvt_kernel<<<dim3(256), dim3(256), 0, stream>>>(Wv, Wvb, CC * CC, flag);
  cvt_kernel<<<dim3(1), dim3(256), 0, stream>>>(bq, bqb, CC, flag);
  cvt_kernel<<<dim3(1), dim3(256), 0, stream>>>(bk, bkb, CC, flag);
  cvt_kernel<<<dim3(1), dim3(256), 0, stream>>>(bv, bvb, CC, flag);
  cvt_kernel<<<dim3(1), dim3(256), 0, stream>>>(gamma, gmb, CC, flag);
  cvt_kernel<<<dim3(1), dim3(256), 0, stream>>>(beta, btb, CC, flag);
  stats_kernel<<<dim3(BB * TT / 4), dim3(256), 0, stream>>>(x, stats, flag);

  if (full) {
    qkv_kernel<<<dim3(32, 2, BB), dim3(256), 0, stream>>>(x, stats, gmb, btb, Wqb, bqb,
                                                          qb, 0, 0, flag);
    qkv_kernel<<<dim3(32, 2, BB), dim3(256), 0, stream>>>(x, stats, gmb, btb, Wkb, bkb,
                                                          kb, 0, 0, flag);
    qkv_kernel<<<dim3(32, 2, BB), dim3(256), 0, stream>>>(x, stats, gmb, btb, Wvb, bvb,
                                                          vtb, 0, 1, flag);
    zsum_kernel<<<dim3(64, BB), dim3(256), 0, stream>>>(qb, kb, Mg, zinv);
    attn_kernel<<<dim3(64, BB), dim3(256), 0, stream>>>(qb, kb, vtb, Mg, zinv, x, out, 0,
                                                        flag);
  } else {
    for (int b = 0; b < BB; b++) {
      int row0 = b * TT;
      qkv_kernel<<<dim3(32, 2, 1), dim3(256), 0, stream>>>(x, stats, gmb, btb, Wqb, bqb,
                                                           qb, row0, 0, flag);
      qkv_kernel<<<dim3(32, 2, 1), dim3(256), 0, stream>>>(x, stats, gmb, btb, Wkb, bkb,
                                                           kb, row0, 0, flag);
      qkv_kernel<<<dim3(32, 2, 1), dim3(256), 0, stream>>>(x, stats, gmb, btb, Wvb, bvb,
                                                           vtb, row0, 1, flag);
      zsum_kernel<<<dim3(64, 1), dim3(256), 0, stream>>>(qb, kb, Mg, zinv);
      attn_kernel<<<dim3(64, 1), dim3(256), 0, stream>>>(qb, kb, vtb, Mg, zinv, x, out,
                                                         row0, flag);
    }
  }
}

// Round 8
// 534.936 us; speedup vs baseline: 3.9028x; 1.1508x over previous
//
#include <hip/hip_runtime.h>

#define BB 4
#define TT 4096
#define CC 256

typedef __attribute__((ext_vector_type(8))) short short8;   // 8 x bf16 (4 VGPRs)
typedef __attribute__((ext_vector_type(4))) float f32x4;

#define SCALE 0.0625f  // C^-0.5 = 1/16
#define ECLAMP 60.0f   // exp-arg clamp, identical in zsum & attn

__device__ __forceinline__ float bf2f(unsigned short u) {
  union { unsigned int i; float f; } v; v.i = ((unsigned int)u) << 16; return v.f;
}
__device__ __forceinline__ unsigned short f2bf(float f) {
  union { float f; unsigned int i; } v; v.f = f;
  unsigned int x = v.i;
  unsigned int r = x + 0x7fffu + ((x >> 16) & 1u);  // RNE
  return (unsigned short)(r >> 16);
}

// ---------------- K0: input dtype detection ----------------
__global__ __launch_bounds__(256) void detect_kernel(const unsigned short* __restrict__ xu,
                                                     int* __restrict__ flag) {
  __shared__ int part[4];
  int tid = threadIdx.x;
  int cnt = 0;
#pragma unroll
  for (int i = 0; i < 32; i++) {
    unsigned short u = xu[tid * 32 + i];
    int e = (u >> 7) & 0xff;
    cnt += (e >= 0xC0) ? 1 : 0;
  }
#pragma unroll
  for (int off = 32; off >= 1; off >>= 1) cnt += __shfl_xor(cnt, off);
  if ((tid & 63) == 0) part[tid >> 6] = cnt;
  __syncthreads();
  if (tid == 0) flag[0] = (part[0] + part[1] + part[2] + part[3] > 64) ? 1 : 0;
}

// ---------------- K0b: convert input array to bf16 ws copy ----------------
__global__ __launch_bounds__(256) void cvt_kernel(const void* __restrict__ src,
                                                  unsigned short* __restrict__ dst, int n,
                                                  const int* __restrict__ flag) {
  int i = blockIdx.x * 256 + threadIdx.x;
  if (i >= n) return;
  if (*flag)
    dst[i] = f2bf(((const float*)src)[i]);
  else
    dst[i] = ((const unsigned short*)src)[i];
}

// ---------------- K1: LayerNorm row stats (mu, rsqrt(var+eps)) ----------------
__global__ __launch_bounds__(256) void stats_kernel(const void* __restrict__ xv,
                                                    float2* __restrict__ stats,
                                                    const int* __restrict__ flagp) {
  int row = blockIdx.x * 4 + (threadIdx.x >> 6);
  int lane = threadIdx.x & 63;
  float f0, f1, f2, f3;
  if (*flagp) {
    const float* xr = (const float*)xv + (size_t)row * CC + lane * 4;
    float4 v = *(const float4*)xr;
    f0 = v.x; f1 = v.y; f2 = v.z; f3 = v.w;
  } else {
    const unsigned short* xr = (const unsigned short*)xv + (size_t)row * CC + lane * 4;
    uint2 v = *(const uint2*)xr;
    f0 = bf2f(v.x & 0xffffu); f1 = bf2f(v.x >> 16);
    f2 = bf2f(v.y & 0xffffu); f3 = bf2f(v.y >> 16);
  }
  float s = f0 + f1 + f2 + f3;
  float s2 = f0 * f0 + f1 * f1 + f2 * f2 + f3 * f3;
#pragma unroll
  for (int off = 32; off >= 1; off >>= 1) {
    s += __shfl_xor(s, off);
    s2 += __shfl_xor(s2, off);
  }
  if (lane == 0) {
    float mu = s * (1.0f / CC);
    float var = s2 * (1.0f / CC) - mu * mu;
    stats[row] = make_float2(mu, rsqrtf(var + 1e-5f));
  }
}

// ---------------- K2: fused LN + projection GEMM (unchanged from R7) --------
__global__ __launch_bounds__(256) void qkv_kernel(
    const void* __restrict__ xv, const float2* __restrict__ stats,
    const unsigned short* __restrict__ gmb, const unsigned short* __restrict__ btb,
    const unsigned short* __restrict__ Wb, const unsigned short* __restrict__ biasb,
    unsigned short* __restrict__ outp, int row0, int transposed,
    const int* __restrict__ flagp) {
  constexpr int LD = 56;
  alignas(16) __shared__ unsigned short As[128 * LD];
  alignas(16) __shared__ unsigned short Bs[128 * LD];
  __shared__ float gf[CC], bfv[CC];
  int tid = threadIdx.x;
  int flag = *flagp;
  gf[tid] = bf2f(gmb[tid]);
  bfv[tid] = bf2f(btb[tid]);
  int row0e = row0 + blockIdx.z * TT;
  unsigned short* outpe = outp + (size_t)blockIdx.z * TT * CC;
  int m0 = blockIdx.x * 128, n0 = blockIdx.y * 128;
  int wid = tid >> 6, lane = tid & 63, qd = lane >> 4, l15 = lane & 15;
  int wm = wid >> 1, wn = wid & 1;
  f32x4 acc[4][4] = {};
  int srow = tid >> 2, sc8 = (tid & 3) * 8;
  float2 st0 = stats[row0e + m0 + srow];
  float2 st1 = stats[row0e + m0 + srow + 64];
  for (int kk = 0; kk < 8; kk++) {
    int k0 = kk * 32;
    __syncthreads();
#pragma unroll
    for (int rr = 0; rr < 2; rr++) {
      int r = srow + rr * 64;
      float2 st = rr ? st1 : st0;
      float v[8];
      if (flag) {
        const float* xr = (const float*)xv + (size_t)(row0e + m0 + r) * CC + k0 + sc8;
        float4 a = *(const float4*)xr;
        float4 b2 = *(const float4*)(xr + 4);
        v[0] = a.x; v[1] = a.y; v[2] = a.z; v[3] = a.w;
        v[4] = b2.x; v[5] = b2.y; v[6] = b2.z; v[7] = b2.w;
      } else {
        uint4 u = *(const uint4*)((const unsigned short*)xv +
                                  (size_t)(row0e + m0 + r) * CC + k0 + sc8);
        v[0] = bf2f(u.x & 0xffffu); v[1] = bf2f(u.x >> 16);
        v[2] = bf2f(u.y & 0xffffu); v[3] = bf2f(u.y >> 16);
        v[4] = bf2f(u.z & 0xffffu); v[5] = bf2f(u.z >> 16);
        v[6] = bf2f(u.w & 0xffffu); v[7] = bf2f(u.w >> 16);
      }
      union { unsigned short s[8]; uint4 u; } o;
#pragma unroll
      for (int j = 0; j < 8; j++)
        o.s[j] = f2bf((v[j] - st.x) * st.y * gf[k0 + sc8 + j] + bfv[k0 + sc8 + j]);
      *(uint4*)&As[r * LD + sc8] = o.u;
    }
    *(uint4*)&Bs[srow * LD + sc8] =
        *(const uint4*)(Wb + (size_t)(n0 + srow) * CC + k0 + sc8);
    *(uint4*)&Bs[(srow + 64) * LD + sc8] =
        *(const uint4*)(Wb + (size_t)(n0 + srow + 64) * CC + k0 + sc8);
    __syncthreads();
    short8 a[4], bfr[4];
#pragma unroll
    for (int mi = 0; mi < 4; mi++)
      a[mi] = *(const short8*)&As[(wm * 64 + mi * 16 + l15) * LD + qd * 8];
#pragma unroll
    for (int ni = 0; ni < 4; ni++)
      bfr[ni] = *(const short8*)&Bs[(wn * 64 + ni * 16 + l15) * LD + qd * 8];
#pragma unroll
    for (int mi = 0; mi < 4; mi++)
#pragma unroll
      for (int ni = 0; ni < 4; ni++)
        acc[mi][ni] =
            __builtin_amdgcn_mfma_f32_16x16x32_bf16(a[mi], bfr[ni], acc[mi][ni], 0, 0, 0);
  }
#pragma unroll
  for (int mi = 0; mi < 4; mi++)
#pragma unroll
    for (int ni = 0; ni < 4; ni++) {
      int n = n0 + wn * 64 + ni * 16 + l15;
      float bsv = bf2f(biasb[n]);
#pragma unroll
      for (int r = 0; r < 4; r++) {
        int m = m0 + wm * 64 + mi * 16 + qd * 4 + r;
        unsigned short val = f2bf(acc[mi][ni][r] + bsv);
        if (transposed)
          outpe[(size_t)n * TT + m] = val;
        else
          outpe[(size_t)m * CC + n] = val;
      }
    }
}

// ---------------- K3: zsum v3 — barrier-free streaming ----------------
// Z_t = sum_s exp(S[t,s]*scale); A = Q[t-tile 32] in registers, B = K direct.
__global__ __launch_bounds__(256) void zsum_kernel(
    const unsigned short* __restrict__ q, const unsigned short* __restrict__ k,
    float* __restrict__ zinvp, int swiz) {
  __shared__ float Zp[4][32];
  int bx = blockIdx.x;
  int batch = swiz ? ((bx & 7) >> 1) : 0;
  int tile = swiz ? ((bx >> 3) * 2 + (bx & 1)) : bx;
  const unsigned short* qb = q + (size_t)batch * TT * CC;
  const unsigned short* kb = k + (size_t)batch * TT * CC;
  float* zinv = zinvp + (size_t)batch * TT;
  int tid = threadIdx.x, wid = tid >> 6, lane = tid & 63, qd = lane >> 4, l15 = lane & 15;
  int t0 = tile * 32;
  short8 afix[2][8];
#pragma unroll
  for (int mi = 0; mi < 2; mi++)
#pragma unroll
    for (int kk = 0; kk < 8; kk++)
      afix[mi][kk] =
          *(const short8*)(qb + (size_t)(t0 + mi * 16 + l15) * CC + kk * 32 + qd * 8);
  float zacc[2][4] = {};
  const unsigned short* kbase = kb + (size_t)(wid * 32 + l15) * CC + qd * 8;
  for (int sc = 0; sc < TT; sc += 128) {
    f32x4 sacc[2][2] = {};
#pragma unroll
    for (int kk = 0; kk < 8; kk++) {
      short8 b0 = *(const short8*)(kbase + (size_t)sc * CC + kk * 32);
      short8 b1 = *(const short8*)(kbase + (size_t)(sc + 16) * CC + kk * 32);
      sacc[0][0] = __builtin_amdgcn_mfma_f32_16x16x32_bf16(afix[0][kk], b0, sacc[0][0], 0, 0, 0);
      sacc[1][0] = __builtin_amdgcn_mfma_f32_16x16x32_bf16(afix[1][kk], b0, sacc[1][0], 0, 0, 0);
      sacc[0][1] = __builtin_amdgcn_mfma_f32_16x16x32_bf16(afix[0][kk], b1, sacc[0][1], 0, 0, 0);
      sacc[1][1] = __builtin_amdgcn_mfma_f32_16x16x32_bf16(afix[1][kk], b1, sacc[1][1], 0, 0, 0);
    }
#pragma unroll
    for (int mi = 0; mi < 2; mi++)
#pragma unroll
      for (int r = 0; r < 4; r++)
        zacc[mi][r] += __expf(fminf(sacc[mi][0][r] * SCALE, ECLAMP)) +
                       __expf(fminf(sacc[mi][1][r] * SCALE, ECLAMP));
  }
#pragma unroll
  for (int mi = 0; mi < 2; mi++)
#pragma unroll
    for (int r = 0; r < 4; r++) {
      float z = zacc[mi][r];
      z += __shfl_xor(z, 1); z += __shfl_xor(z, 2);
      z += __shfl_xor(z, 4); z += __shfl_xor(z, 8);
      zacc[mi][r] = z;
    }
  if (l15 == 0) {
#pragma unroll
    for (int mi = 0; mi < 2; mi++)
#pragma unroll
      for (int r = 0; r < 4; r++) Zp[wid][mi * 16 + qd * 4 + r] = zacc[mi][r];
  }
  __syncthreads();
  if (tid < 32) {
    float Z = Zp[0][tid] + Zp[1][tid] + Zp[2][tid] + Zp[3][tid];
    zinv[t0 + tid] = 1.0f / Z;
  }
}

// ---------------- K4: attn v3 — reg-A S^T, direct-B, 2 barriers/chunk -------
// out[s,c] = x[s,c] + sum_t P[t,s]*v[t,c]; S^T: A=K[s-tile] regs, B=Q direct.
__global__ __launch_bounds__(256) void attn_kernel(
    const unsigned short* __restrict__ q, const unsigned short* __restrict__ k,
    const unsigned short* __restrict__ vt, const float* __restrict__ zinvp,
    const void* __restrict__ xv, float* __restrict__ out, int swiz, int row0,
    const int* __restrict__ flagp) {
  constexpr int LPt = 136;  // 272 B row stride, 16B-aligned
  alignas(16) __shared__ unsigned short Pt[32 * LPt];  // 8.7 KB only
  int bx = blockIdx.x;
  int batch = swiz ? ((bx & 7) >> 1) : 0;
  int tile = swiz ? ((bx >> 3) * 2 + (bx & 1)) : bx;
  int flag = *flagp;
  const unsigned short* qb = q + (size_t)batch * TT * CC;
  const unsigned short* kb = k + (size_t)batch * TT * CC;
  const unsigned short* vtb = vt + (size_t)batch * TT * CC;  // [c][t]
  const float* zinv = zinvp + (size_t)batch * TT;
  int row0e = swiz ? batch * TT : row0;
  int tid = threadIdx.x, wid = tid >> 6, lane = tid & 63, qd = lane >> 4, l15 = lane & 15;
  int s0 = tile * 32;
  // A-fixed: K[s0 + mi*16 + l15][kk*32 + qd*8]
  short8 afix[2][8];
#pragma unroll
  for (int mi = 0; mi < 2; mi++)
#pragma unroll
    for (int kk = 0; kk < 8; kk++)
      afix[mi][kk] =
          *(const short8*)(kb + (size_t)(s0 + mi * 16 + l15) * CC + kk * 32 + qd * 8);
  f32x4 oacc[2][4] = {};
  const unsigned short* qrow = qb + (size_t)(wid * 32 + l15) * CC + qd * 8;
  const unsigned short* vrow[4];
#pragma unroll
  for (int ni = 0; ni < 4; ni++)
    vrow[ni] = vtb + (size_t)(wid * 64 + ni * 16 + l15) * TT + qd * 8;
  for (int tc = 0; tc < TT; tc += 128) {
    // ---- S^T phase: sacc[mi][ni], m=s, n=t (no LDS) ----
    f32x4 sacc[2][2] = {};
#pragma unroll
    for (int kk = 0; kk < 8; kk++) {
      short8 b0 = *(const short8*)(qrow + (size_t)tc * CC + kk * 32);
      short8 b1 = *(const short8*)(qrow + (size_t)(tc + 16) * CC + kk * 32);
      sacc[0][0] = __builtin_amdgcn_mfma_f32_16x16x32_bf16(afix[0][kk], b0, sacc[0][0], 0, 0, 0);
      sacc[1][0] = __builtin_amdgcn_mfma_f32_16x16x32_bf16(afix[1][kk], b0, sacc[1][0], 0, 0, 0);
      sacc[0][1] = __builtin_amdgcn_mfma_f32_16x16x32_bf16(afix[0][kk], b1, sacc[0][1], 0, 0, 0);
      sacc[1][1] = __builtin_amdgcn_mfma_f32_16x16x32_bf16(afix[1][kk], b1, sacc[1][1], 0, 0, 0);
    }
    float zv0 = zinv[tc + wid * 32 + l15];
    float zv1 = zinv[tc + wid * 32 + 16 + l15];
    __syncthreads();  // previous chunk's PV reads of Pt complete
    // P^T -> LDS: row = s_local (C/D row = qd*4+r), col = t_local (= l15-col)
#pragma unroll
    for (int mi = 0; mi < 2; mi++)
#pragma unroll
      for (int ni = 0; ni < 2; ni++) {
        int t_loc = wid * 32 + ni * 16 + l15;
        float zz = ni ? zv1 : zv0;
#pragma unroll
        for (int r = 0; r < 4; r++) {
          float p = __expf(fminf(sacc[mi][ni][r] * SCALE, ECLAMP)) * zz;
          Pt[(mi * 16 + qd * 4 + r) * LPt + t_loc] = f2bf(p);
        }
      }
    __syncthreads();
    // ---- PV phase: oacc[s,c] += P^T[s,t] * Vt[c,t] ----
#pragma unroll
    for (int kt = 0; kt < 4; kt++) {
      short8 a0 = *(const short8*)&Pt[l15 * LPt + kt * 32 + qd * 8];
      short8 a1 = *(const short8*)&Pt[(16 + l15) * LPt + kt * 32 + qd * 8];
#pragma unroll
      for (int ni = 0; ni < 4; ni++) {
        short8 b = *(const short8*)(vrow[ni] + tc + kt * 32);
        oacc[0][ni] = __builtin_amdgcn_mfma_f32_16x16x32_bf16(a0, b, oacc[0][ni], 0, 0, 0);
        oacc[1][ni] = __builtin_amdgcn_mfma_f32_16x16x32_bf16(a1, b, oacc[1][ni], 0, 0, 0);
      }
    }
  }
  // epilogue: out(f32) = oacc + x
#pragma unroll
  for (int mi = 0; mi < 2; mi++)
#pragma unroll
    for (int ni = 0; ni < 4; ni++)
#pragma unroll
      for (int r = 0; r < 4; r++) {
        int s = s0 + mi * 16 + qd * 4 + r;
        int c = wid * 64 + ni * 16 + l15;
        size_t idx = ((size_t)(row0e + s)) * CC + c;
        float xr = flag ? ((const float*)xv)[idx] : bf2f(((const unsigned short*)xv)[idx]);
        out[idx] = oacc[mi][ni][r] + xr;
      }
}

extern "C" void kernel_launch(void* const* d_in, const int* in_sizes, int n_in,
                              void* d_out, int out_size, void* d_ws, size_t ws_size,
                              hipStream_t stream) {
  const void* x = d_in[0];
  const void* gamma = d_in[1];
  const void* beta = d_in[2];
  const void* Wq = d_in[3];
  const void* bq = d_in[4];
  const void* Wk = d_in[5];
  const void* bk = d_in[6];
  const void* Wv = d_in[7];
  const void* bv = d_in[8];
  float* out = (float*)d_out;  // reference output dtype: float32

  char* ws = (char*)d_ws;
  int* flag = (int*)(ws + 0);
  float2* stats = (float2*)(ws + 1024);                      // 128 KiB
  unsigned short* gmb = (unsigned short*)(ws + 132096);
  unsigned short* btb = (unsigned short*)(ws + 132608);
  unsigned short* bqb = (unsigned short*)(ws + 133120);
  unsigned short* bkb = (unsigned short*)(ws + 133632);
  unsigned short* bvb = (unsigned short*)(ws + 134144);
  unsigned short* Wqb = (unsigned short*)(ws + 135168);      // 128 KiB each
  unsigned short* Wkb = (unsigned short*)(ws + 266240);
  unsigned short* Wvb = (unsigned short*)(ws + 397312);
  float* zinv = (float*)(ws + 593920);                       // 64 KiB
  unsigned short* qb = (unsigned short*)(ws + 1048576);
  const int full = (ws_size >= 26214400u);
  size_t qkv_bytes = full ? 8388608u : 2097152u;
  unsigned short* kb = (unsigned short*)((char*)qb + qkv_bytes);
  unsigned short* vtb = (unsigned short*)((char*)kb + qkv_bytes);  // V^T [b][c][t]

  detect_kernel<<<dim3(1), dim3(256), 0, stream>>>((const unsigned short*)x, flag);
  cvt_kernel<<<dim3(256), dim3(256), 0, stream>>>(Wq, Wqb, CC * CC, flag);
  cvt_kernel<<<dim3(256), dim3(256), 0, stream>>>(Wk, Wkb, CC * CC, flag);
  cvt_kernel<<<dim3(256), dim3(256), 0, stream>>>(Wv, Wvb, CC * CC, flag);
  cvt_kernel<<<dim3(1), dim3(256), 0, stream>>>(bq, bqb, CC, flag);
  cvt_kernel<<<dim3(1), dim3(256), 0, stream>>>(bk, bkb, CC, flag);
  cvt_kernel<<<dim3(1), dim3(256), 0, stream>>>(bv, bvb, CC, flag);
  cvt_kernel<<<dim3(1), dim3(256), 0, stream>>>(gamma, gmb, CC, flag);
  cvt_kernel<<<dim3(1), dim3(256), 0, stream>>>(beta, btb, CC, flag);
  stats_kernel<<<dim3(BB * TT / 4), dim3(256), 0, stream>>>(x, stats, flag);

  if (full) {
    qkv_kernel<<<dim3(32, 2, BB), dim3(256), 0, stream>>>(x, stats, gmb, btb, Wqb, bqb,
                                                          qb, 0, 0, flag);
    qkv_kernel<<<dim3(32, 2, BB), dim3(256), 0, stream>>>(x, stats, gmb, btb, Wkb, bkb,
                                                          kb, 0, 0, flag);
    qkv_kernel<<<dim3(32, 2, BB), dim3(256), 0, stream>>>(x, stats, gmb, btb, Wvb, bvb,
                                                          vtb, 0, 1, flag);
    zsum_kernel<<<dim3(512), dim3(256), 0, stream>>>(qb, kb, zinv, 1);
    attn_kernel<<<dim3(512), dim3(256), 0, stream>>>(qb, kb, vtb, zinv, x, out, 1, 0,
                                                     flag);
  } else {
    for (int b = 0; b < BB; b++) {
      int row0 = b * TT;
      qkv_kernel<<<dim3(32, 2, 1), dim3(256), 0, stream>>>(x, stats, gmb, btb, Wqb, bqb,
                                                           qb, row0, 0, flag);
      qkv_kernel<<<dim3(32, 2, 1), dim3(256), 0, stream>>>(x, stats, gmb, btb, Wkb, bkb,
                                                           kb, row0, 0, flag);
      qkv_kernel<<<dim3(32, 2, 1), dim3(256), 0, stream>>>(x, stats, gmb, btb, Wvb, bvb,
                                                           vtb, row0, 1, flag);
      zsum_kernel<<<dim3(128), dim3(256), 0, stream>>>(qb, kb, zinv, 0);
      attn_kernel<<<dim3(128), dim3(256), 0, stream>>>(qb, kb, vtb, zinv, x, out, 0, row0,
                                                       flag);
    }
  }
}

// Round 9
// 507.023 us; speedup vs baseline: 4.1177x; 1.0551x over previous
//
#include <hip/hip_runtime.h>

#define BB 4
#define TT 4096
#define CC 256

typedef __attribute__((ext_vector_type(8))) short short8;   // 8 x bf16 (4 VGPRs)
typedef __attribute__((ext_vector_type(4))) float f32x4;

#define SCALE 0.0625f  // C^-0.5 = 1/16
#define ECLAMP 60.0f   // exp-arg clamp, identical in zsum & attn

__device__ __forceinline__ float bf2f(unsigned short u) {
  union { unsigned int i; float f; } v; v.i = ((unsigned int)u) << 16; return v.f;
}
__device__ __forceinline__ unsigned short f2bf(float f) {
  union { float f; unsigned int i; } v; v.f = f;
  unsigned int x = v.i;
  unsigned int r = x + 0x7fffu + ((x >> 16) & 1u);  // RNE
  return (unsigned short)(r >> 16);
}

// ---------------- K0: input dtype detection ----------------
__global__ __launch_bounds__(256) void detect_kernel(const unsigned short* __restrict__ xu,
                                                     int* __restrict__ flag) {
  __shared__ int part[4];
  int tid = threadIdx.x;
  int cnt = 0;
#pragma unroll
  for (int i = 0; i < 32; i++) {
    unsigned short u = xu[tid * 32 + i];
    int e = (u >> 7) & 0xff;
    cnt += (e >= 0xC0) ? 1 : 0;
  }
#pragma unroll
  for (int off = 32; off >= 1; off >>= 1) cnt += __shfl_xor(cnt, off);
  if ((tid & 63) == 0) part[tid >> 6] = cnt;
  __syncthreads();
  if (tid == 0) flag[0] = (part[0] + part[1] + part[2] + part[3] > 64) ? 1 : 0;
}

// ---------------- K0b: convert input array to bf16 ws copy ----------------
__global__ __launch_bounds__(256) void cvt_kernel(const void* __restrict__ src,
                                                  unsigned short* __restrict__ dst, int n,
                                                  const int* __restrict__ flag) {
  int i = blockIdx.x * 256 + threadIdx.x;
  if (i >= n) return;
  if (*flag)
    dst[i] = f2bf(((const float*)src)[i]);
  else
    dst[i] = ((const unsigned short*)src)[i];
}

// ---------------- K1: LayerNorm row stats (mu, rsqrt(var+eps)) ----------------
__global__ __launch_bounds__(256) void stats_kernel(const void* __restrict__ xv,
                                                    float2* __restrict__ stats,
                                                    const int* __restrict__ flagp) {
  int row = blockIdx.x * 4 + (threadIdx.x >> 6);
  int lane = threadIdx.x & 63;
  float f0, f1, f2, f3;
  if (*flagp) {
    const float* xr = (const float*)xv + (size_t)row * CC + lane * 4;
    float4 v = *(const float4*)xr;
    f0 = v.x; f1 = v.y; f2 = v.z; f3 = v.w;
  } else {
    const unsigned short* xr = (const unsigned short*)xv + (size_t)row * CC + lane * 4;
    uint2 v = *(const uint2*)xr;
    f0 = bf2f(v.x & 0xffffu); f1 = bf2f(v.x >> 16);
    f2 = bf2f(v.y & 0xffffu); f3 = bf2f(v.y >> 16);
  }
  float s = f0 + f1 + f2 + f3;
  float s2 = f0 * f0 + f1 * f1 + f2 * f2 + f3 * f3;
#pragma unroll
  for (int off = 32; off >= 1; off >>= 1) {
    s += __shfl_xor(s, off);
    s2 += __shfl_xor(s2, off);
  }
  if (lane == 0) {
    float mu = s * (1.0f / CC);
    float var = s2 * (1.0f / CC) - mu * mu;
    stats[row] = make_float2(mu, rsqrtf(var + 1e-5f));
  }
}

// ---------------- K2: fused LN + ALL THREE projections in one launch --------
// blockIdx.y: (y>>1) selects W/bias/out among {q,k,v}; (y&1) selects n-half.
__global__ __launch_bounds__(256) void qkv3_kernel(
    const void* __restrict__ xv, const float2* __restrict__ stats,
    const unsigned short* __restrict__ gmb, const unsigned short* __restrict__ btb,
    const unsigned short* __restrict__ Wq, const unsigned short* __restrict__ Wk,
    const unsigned short* __restrict__ Wv, const unsigned short* __restrict__ bq,
    const unsigned short* __restrict__ bk, const unsigned short* __restrict__ bv,
    unsigned short* __restrict__ oq, unsigned short* __restrict__ ok,
    unsigned short* __restrict__ ov, int row0, const int* __restrict__ flagp) {
  constexpr int LD = 56;
  alignas(16) __shared__ unsigned short As[128 * LD];
  alignas(16) __shared__ unsigned short Bs[128 * LD];
  __shared__ float gf[CC], bfv[CC];
  int tid = threadIdx.x;
  int flag = *flagp;
  gf[tid] = bf2f(gmb[tid]);
  bfv[tid] = bf2f(btb[tid]);
  int w = blockIdx.y >> 1;
  const unsigned short* Wb = (w == 0) ? Wq : (w == 1) ? Wk : Wv;
  const unsigned short* biasb = (w == 0) ? bq : (w == 1) ? bk : bv;
  unsigned short* outp = (w == 0) ? oq : (w == 1) ? ok : ov;
  int transposed = (w == 2);
  int row0e = row0 + blockIdx.z * TT;
  unsigned short* outpe = outp + (size_t)blockIdx.z * TT * CC;
  int m0 = blockIdx.x * 128, n0 = (blockIdx.y & 1) * 128;
  int wid = tid >> 6, lane = tid & 63, qd = lane >> 4, l15 = lane & 15;
  int wm = wid >> 1, wn = wid & 1;
  f32x4 acc[4][4] = {};
  int srow = tid >> 2, sc8 = (tid & 3) * 8;
  float2 st0 = stats[row0e + m0 + srow];
  float2 st1 = stats[row0e + m0 + srow + 64];
  for (int kk = 0; kk < 8; kk++) {
    int k0 = kk * 32;
    __syncthreads();
#pragma unroll
    for (int rr = 0; rr < 2; rr++) {
      int r = srow + rr * 64;
      float2 st = rr ? st1 : st0;
      float v[8];
      if (flag) {
        const float* xr = (const float*)xv + (size_t)(row0e + m0 + r) * CC + k0 + sc8;
        float4 a = *(const float4*)xr;
        float4 b2 = *(const float4*)(xr + 4);
        v[0] = a.x; v[1] = a.y; v[2] = a.z; v[3] = a.w;
        v[4] = b2.x; v[5] = b2.y; v[6] = b2.z; v[7] = b2.w;
      } else {
        uint4 u = *(const uint4*)((const unsigned short*)xv +
                                  (size_t)(row0e + m0 + r) * CC + k0 + sc8);
        v[0] = bf2f(u.x & 0xffffu); v[1] = bf2f(u.x >> 16);
        v[2] = bf2f(u.y & 0xffffu); v[3] = bf2f(u.y >> 16);
        v[4] = bf2f(u.z & 0xffffu); v[5] = bf2f(u.z >> 16);
        v[6] = bf2f(u.w & 0xffffu); v[7] = bf2f(u.w >> 16);
      }
      union { unsigned short s[8]; uint4 u; } o;
#pragma unroll
      for (int j = 0; j < 8; j++)
        o.s[j] = f2bf((v[j] - st.x) * st.y * gf[k0 + sc8 + j] + bfv[k0 + sc8 + j]);
      *(uint4*)&As[r * LD + sc8] = o.u;
    }
    *(uint4*)&Bs[srow * LD + sc8] =
        *(const uint4*)(Wb + (size_t)(n0 + srow) * CC + k0 + sc8);
    *(uint4*)&Bs[(srow + 64) * LD + sc8] =
        *(const uint4*)(Wb + (size_t)(n0 + srow + 64) * CC + k0 + sc8);
    __syncthreads();
    short8 a[4], bfr[4];
#pragma unroll
    for (int mi = 0; mi < 4; mi++)
      a[mi] = *(const short8*)&As[(wm * 64 + mi * 16 + l15) * LD + qd * 8];
#pragma unroll
    for (int ni = 0; ni < 4; ni++)
      bfr[ni] = *(const short8*)&Bs[(wn * 64 + ni * 16 + l15) * LD + qd * 8];
#pragma unroll
    for (int mi = 0; mi < 4; mi++)
#pragma unroll
      for (int ni = 0; ni < 4; ni++)
        acc[mi][ni] =
            __builtin_amdgcn_mfma_f32_16x16x32_bf16(a[mi], bfr[ni], acc[mi][ni], 0, 0, 0);
  }
#pragma unroll
  for (int mi = 0; mi < 4; mi++)
#pragma unroll
    for (int ni = 0; ni < 4; ni++) {
      int n = n0 + wn * 64 + ni * 16 + l15;
      float bsv = bf2f(biasb[n]);
#pragma unroll
      for (int r = 0; r < 4; r++) {
        int m = m0 + wm * 64 + mi * 16 + qd * 4 + r;
        unsigned short val = f2bf(acc[mi][ni][r] + bsv);
        if (transposed)
          outpe[(size_t)n * TT + m] = val;
        else
          outpe[(size_t)m * CC + n] = val;
      }
    }
}

// ---------------- K3: zsum v4 — barrier-free, register-ping-pong ----------------
__global__ __launch_bounds__(256, 2) void zsum_kernel(
    const unsigned short* __restrict__ q, const unsigned short* __restrict__ k,
    float* __restrict__ zinvp, int swiz) {
  __shared__ float Zp[4][32];
  int bx = blockIdx.x;
  int batch = swiz ? ((bx & 7) >> 1) : 0;
  int tile = swiz ? ((bx >> 3) * 2 + (bx & 1)) : bx;
  const unsigned short* qb = q + (size_t)batch * TT * CC;
  const unsigned short* kb = k + (size_t)batch * TT * CC;
  float* zinv = zinvp + (size_t)batch * TT;
  int tid = threadIdx.x, wid = tid >> 6, lane = tid & 63, qd = lane >> 4, l15 = lane & 15;
  int t0 = tile * 32;
  short8 afix[2][8];
#pragma unroll
  for (int mi = 0; mi < 2; mi++)
#pragma unroll
    for (int kk = 0; kk < 8; kk++)
      afix[mi][kk] =
          *(const short8*)(qb + (size_t)(t0 + mi * 16 + l15) * CC + kk * 32 + qd * 8);
  float zacc[2][4] = {};
  const unsigned short* kbase = kb + (size_t)(wid * 32 + l15) * CC + qd * 8;
  short8 b0[16], b1[16];
#pragma unroll
  for (int kk = 0; kk < 8; kk++) {
    b0[kk * 2] = *(const short8*)(kbase + (size_t)0 * CC + kk * 32);
    b0[kk * 2 + 1] = *(const short8*)(kbase + (size_t)16 * CC + kk * 32);
  }
  for (int sc = 0; sc < TT; sc += 256) {
    // prefetch chunk sc+128 into b1, compute on b0
#pragma unroll
    for (int kk = 0; kk < 8; kk++) {
      b1[kk * 2] = *(const short8*)(kbase + (size_t)(sc + 128) * CC + kk * 32);
      b1[kk * 2 + 1] = *(const short8*)(kbase + (size_t)(sc + 144) * CC + kk * 32);
    }
    {
      f32x4 sacc[2][2] = {};
#pragma unroll
      for (int kk = 0; kk < 8; kk++) {
        sacc[0][0] = __builtin_amdgcn_mfma_f32_16x16x32_bf16(afix[0][kk], b0[kk * 2], sacc[0][0], 0, 0, 0);
        sacc[1][0] = __builtin_amdgcn_mfma_f32_16x16x32_bf16(afix[1][kk], b0[kk * 2], sacc[1][0], 0, 0, 0);
        sacc[0][1] = __builtin_amdgcn_mfma_f32_16x16x32_bf16(afix[0][kk], b0[kk * 2 + 1], sacc[0][1], 0, 0, 0);
        sacc[1][1] = __builtin_amdgcn_mfma_f32_16x16x32_bf16(afix[1][kk], b0[kk * 2 + 1], sacc[1][1], 0, 0, 0);
      }
#pragma unroll
      for (int mi = 0; mi < 2; mi++)
#pragma unroll
        for (int r = 0; r < 4; r++)
          zacc[mi][r] += __expf(fminf(sacc[mi][0][r] * SCALE, ECLAMP)) +
                         __expf(fminf(sacc[mi][1][r] * SCALE, ECLAMP));
    }
    // prefetch chunk sc+256 (wrap-safe, last iter loads chunk 0 unused) into b0
    int nn = (sc + 256) & (TT - 1);
#pragma unroll
    for (int kk = 0; kk < 8; kk++) {
      b0[kk * 2] = *(const short8*)(kbase + (size_t)nn * CC + kk * 32);
      b0[kk * 2 + 1] = *(const short8*)(kbase + (size_t)(nn + 16) * CC + kk * 32);
    }
    {
      f32x4 sacc[2][2] = {};
#pragma unroll
      for (int kk = 0; kk < 8; kk++) {
        sacc[0][0] = __builtin_amdgcn_mfma_f32_16x16x32_bf16(afix[0][kk], b1[kk * 2], sacc[0][0], 0, 0, 0);
        sacc[1][0] = __builtin_amdgcn_mfma_f32_16x16x32_bf16(afix[1][kk], b1[kk * 2], sacc[1][0], 0, 0, 0);
        sacc[0][1] = __builtin_amdgcn_mfma_f32_16x16x32_bf16(afix[0][kk], b1[kk * 2 + 1], sacc[0][1], 0, 0, 0);
        sacc[1][1] = __builtin_amdgcn_mfma_f32_16x16x32_bf16(afix[1][kk], b1[kk * 2 + 1], sacc[1][1], 0, 0, 0);
      }
#pragma unroll
      for (int mi = 0; mi < 2; mi++)
#pragma unroll
        for (int r = 0; r < 4; r++)
          zacc[mi][r] += __expf(fminf(sacc[mi][0][r] * SCALE, ECLAMP)) +
                         __expf(fminf(sacc[mi][1][r] * SCALE, ECLAMP));
    }
  }
#pragma unroll
  for (int mi = 0; mi < 2; mi++)
#pragma unroll
    for (int r = 0; r < 4; r++) {
      float z = zacc[mi][r];
      z += __shfl_xor(z, 1); z += __shfl_xor(z, 2);
      z += __shfl_xor(z, 4); z += __shfl_xor(z, 8);
      zacc[mi][r] = z;
    }
  if (l15 == 0) {
#pragma unroll
    for (int mi = 0; mi < 2; mi++)
#pragma unroll
      for (int r = 0; r < 4; r++) Zp[wid][mi * 16 + qd * 4 + r] = zacc[mi][r];
  }
  __syncthreads();
  if (tid < 32) {
    float Z = Zp[0][tid] + Zp[1][tid] + Zp[2][tid] + Zp[3][tid];
    zinv[t0 + tid] = 1.0f / Z;
  }
}

// ---------------- K4: attn v4 — full register pipeline, 1 barrier/chunk -----
__global__ __launch_bounds__(256, 2) void attn_kernel(
    const unsigned short* __restrict__ q, const unsigned short* __restrict__ k,
    const unsigned short* __restrict__ vt, const float* __restrict__ zinvp,
    const void* __restrict__ xv, float* __restrict__ out, int swiz, int row0,
    const int* __restrict__ flagp) {
  constexpr int LPt = 136;  // 272 B row stride
  alignas(16) __shared__ unsigned short Pt[2][32 * LPt];  // double-buffered, 17.4 KB
  int bx = blockIdx.x;
  int batch = swiz ? ((bx & 7) >> 1) : 0;
  int tile = swiz ? ((bx >> 3) * 2 + (bx & 1)) : bx;
  int flag = *flagp;
  const unsigned short* qb = q + (size_t)batch * TT * CC;
  const unsigned short* kb = k + (size_t)batch * TT * CC;
  const unsigned short* vtb = vt + (size_t)batch * TT * CC;  // [c][t]
  const float* zinv = zinvp + (size_t)batch * TT;
  int row0e = swiz ? batch * TT : row0;
  int tid = threadIdx.x, wid = tid >> 6, lane = tid & 63, qd = lane >> 4, l15 = lane & 15;
  int s0 = tile * 32;
  short8 afix[2][8];  // K[s-tile] fixed A operand
#pragma unroll
  for (int mi = 0; mi < 2; mi++)
#pragma unroll
    for (int kk = 0; kk < 8; kk++)
      afix[mi][kk] =
          *(const short8*)(kb + (size_t)(s0 + mi * 16 + l15) * CC + kk * 32 + qd * 8);
  f32x4 oacc[2][4] = {};
  const unsigned short* qrow = qb + (size_t)(wid * 32 + l15) * CC + qd * 8;
  const unsigned short* vrow[4];
#pragma unroll
  for (int ni = 0; ni < 4; ni++)
    vrow[ni] = vtb + (size_t)(wid * 64 + ni * 16 + l15) * TT + qd * 8;
  short8 qbuf[16], vbuf[16];
  // preload chunk 0 Q and V
#pragma unroll
  for (int kk = 0; kk < 8; kk++) {
    qbuf[kk * 2] = *(const short8*)(qrow + (size_t)0 * CC + kk * 32);
    qbuf[kk * 2 + 1] = *(const short8*)(qrow + (size_t)16 * CC + kk * 32);
  }
#pragma unroll
  for (int kt = 0; kt < 4; kt++)
#pragma unroll
    for (int ni = 0; ni < 4; ni++)
      vbuf[kt * 4 + ni] = *(const short8*)(vrow[ni] + 0 + kt * 32);
  for (int tc = 0; tc < TT; tc += 128) {
    int buf = (tc >> 7) & 1;
    int tn = (tc + 128) & (TT - 1);  // wrap-safe prefetch address
    // ---- S^T phase (qbuf) ----
    f32x4 sacc[2][2] = {};
#pragma unroll
    for (int kk = 0; kk < 8; kk++) {
      sacc[0][0] = __builtin_amdgcn_mfma_f32_16x16x32_bf16(afix[0][kk], qbuf[kk * 2], sacc[0][0], 0, 0, 0);
      sacc[1][0] = __builtin_amdgcn_mfma_f32_16x16x32_bf16(afix[1][kk], qbuf[kk * 2], sacc[1][0], 0, 0, 0);
      sacc[0][1] = __builtin_amdgcn_mfma_f32_16x16x32_bf16(afix[0][kk], qbuf[kk * 2 + 1], sacc[0][1], 0, 0, 0);
      sacc[1][1] = __builtin_amdgcn_mfma_f32_16x16x32_bf16(afix[1][kk], qbuf[kk * 2 + 1], sacc[1][1], 0, 0, 0);
    }
    // ---- exp + P^T -> LDS (bf16) ----
    float zv0 = zinv[tc + wid * 32 + l15];
    float zv1 = zinv[tc + wid * 32 + 16 + l15];
#pragma unroll
    for (int mi = 0; mi < 2; mi++)
#pragma unroll
      for (int ni = 0; ni < 2; ni++) {
        int t_loc = wid * 32 + ni * 16 + l15;
        float zz = ni ? zv1 : zv0;
#pragma unroll
        for (int r = 0; r < 4; r++) {
          float p = __expf(fminf(sacc[mi][ni][r] * SCALE, ECLAMP)) * zz;
          Pt[buf][(mi * 16 + qd * 4 + r) * LPt + t_loc] = f2bf(p);
        }
      }
    __syncthreads();  // Pt[buf] visible; drains V(cur) loads (long in flight ~ free)
    // ---- prefetch next chunk's Q (qbuf free now; consumed next S-phase) ----
#pragma unroll
    for (int kk = 0; kk < 8; kk++) {
      qbuf[kk * 2] = *(const short8*)(qrow + (size_t)tn * CC + kk * 32);
      qbuf[kk * 2 + 1] = *(const short8*)(qrow + (size_t)(tn + 16) * CC + kk * 32);
    }
    // ---- PV phase (vbuf + Pt[buf]) ----
#pragma unroll
    for (int kt = 0; kt < 4; kt++) {
      short8 a0 = *(const short8*)&Pt[buf][l15 * LPt + kt * 32 + qd * 8];
      short8 a1 = *(const short8*)&Pt[buf][(16 + l15) * LPt + kt * 32 + qd * 8];
#pragma unroll
      for (int ni = 0; ni < 4; ni++) {
        oacc[0][ni] = __builtin_amdgcn_mfma_f32_16x16x32_bf16(a0, vbuf[kt * 4 + ni], oacc[0][ni], 0, 0, 0);
        oacc[1][ni] = __builtin_amdgcn_mfma_f32_16x16x32_bf16(a1, vbuf[kt * 4 + ni], oacc[1][ni], 0, 0, 0);
      }
    }
    // ---- prefetch next chunk's V (vbuf free; consumed next PV, after barrier) ----
#pragma unroll
    for (int kt = 0; kt < 4; kt++)
#pragma unroll
      for (int ni = 0; ni < 4; ni++)
        vbuf[kt * 4 + ni] = *(const short8*)(vrow[ni] + tn + kt * 32);
  }
  // epilogue: out(f32) = oacc + x
#pragma unroll
  for (int mi = 0; mi < 2; mi++)
#pragma unroll
    for (int ni = 0; ni < 4; ni++)
#pragma unroll
      for (int r = 0; r < 4; r++) {
        int s = s0 + mi * 16 + qd * 4 + r;
        int c = wid * 64 + ni * 16 + l15;
        size_t idx = ((size_t)(row0e + s)) * CC + c;
        float xr = flag ? ((const float*)xv)[idx] : bf2f(((const unsigned short*)xv)[idx]);
        out[idx] = oacc[mi][ni][r] + xr;
      }
}

extern "C" void kernel_launch(void* const* d_in, const int* in_sizes, int n_in,
                              void* d_out, int out_size, void* d_ws, size_t ws_size,
                              hipStream_t stream) {
  const void* x = d_in[0];
  const void* gamma = d_in[1];
  const void* beta = d_in[2];
  const void* Wq = d_in[3];
  const void* bq = d_in[4];
  const void* Wk = d_in[5];
  const void* bk = d_in[6];
  const void* Wv = d_in[7];
  const void* bv = d_in[8];
  float* out = (float*)d_out;  // reference output dtype: float32

  char* ws = (char*)d_ws;
  int* flag = (int*)(ws + 0);
  float2* stats = (float2*)(ws + 1024);                      // 128 KiB
  unsigned short* gmb = (unsigned short*)(ws + 132096);
  unsigned short* btb = (unsigned short*)(ws + 132608);
  unsigned short* bqb = (unsigned short*)(ws + 133120);
  unsigned short* bkb = (unsigned short*)(ws + 133632);
  unsigned short* bvb = (unsigned short*)(ws + 134144);
  unsigned short* Wqb = (unsigned short*)(ws + 135168);      // 128 KiB each
  unsigned short* Wkb = (unsigned short*)(ws + 266240);
  unsigned short* Wvb = (unsigned short*)(ws + 397312);
  float* zinv = (float*)(ws + 593920);                       // 64 KiB
  unsigned short* qb = (unsigned short*)(ws + 1048576);
  const int full = (ws_size >= 26214400u);
  size_t qkv_bytes = full ? 8388608u : 2097152u;
  unsigned short* kb = (unsigned short*)((char*)qb + qkv_bytes);
  unsigned short* vtb = (unsigned short*)((char*)kb + qkv_bytes);  // V^T [b][c][t]

  detect_kernel<<<dim3(1), dim3(256), 0, stream>>>((const unsigned short*)x, flag);
  cvt_kernel<<<dim3(256), dim3(256), 0, stream>>>(Wq, Wqb, CC * CC, flag);
  cvt_kernel<<<dim3(256), dim3(256), 0, stream>>>(Wk, Wkb, CC * CC, flag);
  cvt_kernel<<<dim3(256), dim3(256), 0, stream>>>(Wv, Wvb, CC * CC, flag);
  cvt_kernel<<<dim3(1), dim3(256), 0, stream>>>(bq, bqb, CC, flag);
  cvt_kernel<<<dim3(1), dim3(256), 0, stream>>>(bk, bkb, CC, flag);
  cvt_kernel<<<dim3(1), dim3(256), 0, stream>>>(bv, bvb, CC, flag);
  cvt_kernel<<<dim3(1), dim3(256), 0, stream>>>(gamma, gmb, CC, flag);
  cvt_kernel<<<dim3(1), dim3(256), 0, stream>>>(beta, btb, CC, flag);
  stats_kernel<<<dim3(BB * TT / 4), dim3(256), 0, stream>>>(x, stats, flag);

  if (full) {
    qkv3_kernel<<<dim3(32, 6, BB), dim3(256), 0, stream>>>(
        x, stats, gmb, btb, Wqb, Wkb, Wvb, bqb, bkb, bvb, qb, kb, vtb, 0, flag);
    zsum_kernel<<<dim3(512), dim3(256), 0, stream>>>(qb, kb, zinv, 1);
    attn_kernel<<<dim3(512), dim3(256), 0, stream>>>(qb, kb, vtb, zinv, x, out, 1, 0,
                                                     flag);
  } else {
    for (int b = 0; b < BB; b++) {
      int row0 = b * TT;
      qkv3_kernel<<<dim3(32, 6, 1), dim3(256), 0, stream>>>(
          x, stats, gmb, btb, Wqb, Wkb, Wvb, bqb, bkb, bvb, qb, kb, vtb, row0, flag);
      zsum_kernel<<<dim3(128), dim3(256), 0, stream>>>(qb, kb, zinv, 0);
      attn_kernel<<<dim3(128), dim3(256), 0, stream>>>(qb, kb, vtb, zinv, x, out, 0, row0,
                                                       flag);
    }
  }
}

// Round 10
// 493.649 us; speedup vs baseline: 4.2293x; 1.0271x over previous
//
#include <hip/hip_runtime.h>

#define BB 4
#define TT 4096
#define CC 256

typedef __attribute__((ext_vector_type(8))) short short8;   // 8 x bf16 (4 VGPRs)
typedef __attribute__((ext_vector_type(4))) float f32x4;

#define SCALE 0.0625f  // C^-0.5 = 1/16
#define ECLAMP 60.0f   // exp-arg clamp, identical in zsum & attn

__device__ __forceinline__ float bf2f(unsigned short u) {
  union { unsigned int i; float f; } v; v.i = ((unsigned int)u) << 16; return v.f;
}
__device__ __forceinline__ unsigned short f2bf(float f) {
  union { float f; unsigned int i; } v; v.f = f;
  unsigned int x = v.i;
  unsigned int r = x + 0x7fffu + ((x >> 16) & 1u);  // RNE
  return (unsigned short)(r >> 16);
}

// ---------------- K0: input dtype detection ----------------
__global__ __launch_bounds__(256) void detect_kernel(const unsigned short* __restrict__ xu,
                                                     int* __restrict__ flag) {
  __shared__ int part[4];
  int tid = threadIdx.x;
  int cnt = 0;
#pragma unroll
  for (int i = 0; i < 32; i++) {
    unsigned short u = xu[tid * 32 + i];
    int e = (u >> 7) & 0xff;
    cnt += (e >= 0xC0) ? 1 : 0;
  }
#pragma unroll
  for (int off = 32; off >= 1; off >>= 1) cnt += __shfl_xor(cnt, off);
  if ((tid & 63) == 0) part[tid >> 6] = cnt;
  __syncthreads();
  if (tid == 0) flag[0] = (part[0] + part[1] + part[2] + part[3] > 64) ? 1 : 0;
}

// ---------------- K0b: ALL dtype conversions in ONE launch ----------------
// bx in [0,768): W matrices (256 blocks each); bx in [768,773): the 5 vectors.
__global__ __launch_bounds__(256) void cvt_all_kernel(
    const void* __restrict__ Wq, const void* __restrict__ Wk, const void* __restrict__ Wv,
    const void* __restrict__ bq, const void* __restrict__ bk, const void* __restrict__ bv,
    const void* __restrict__ gm, const void* __restrict__ bt,
    unsigned short* __restrict__ Wqb, unsigned short* __restrict__ Wkb,
    unsigned short* __restrict__ Wvb, unsigned short* __restrict__ bqb,
    unsigned short* __restrict__ bkb, unsigned short* __restrict__ bvb,
    unsigned short* __restrict__ gmb, unsigned short* __restrict__ btb,
    const int* __restrict__ flagp) {
  int bx = blockIdx.x, tid = threadIdx.x;
  const void* src;
  unsigned short* dst;
  int idx;
  if (bx < 256) { src = Wq; dst = Wqb; idx = bx * 256 + tid; }
  else if (bx < 512) { src = Wk; dst = Wkb; idx = (bx - 256) * 256 + tid; }
  else if (bx < 768) { src = Wv; dst = Wvb; idx = (bx - 512) * 256 + tid; }
  else {
    int w = bx - 768; idx = tid;
    src = (w == 0) ? bq : (w == 1) ? bk : (w == 2) ? bv : (w == 3) ? gm : bt;
    dst = (w == 0) ? bqb : (w == 1) ? bkb : (w == 2) ? bvb : (w == 3) ? gmb : btb;
  }
  dst[idx] = (*flagp) ? f2bf(((const float*)src)[idx]) : ((const unsigned short*)src)[idx];
}

// ---------------- K1: LayerNorm row stats (mu, rsqrt(var+eps)) ----------------
__global__ __launch_bounds__(256) void stats_kernel(const void* __restrict__ xv,
                                                    float2* __restrict__ stats,
                                                    const int* __restrict__ flagp) {
  int row = blockIdx.x * 4 + (threadIdx.x >> 6);
  int lane = threadIdx.x & 63;
  float f0, f1, f2, f3;
  if (*flagp) {
    const float* xr = (const float*)xv + (size_t)row * CC + lane * 4;
    float4 v = *(const float4*)xr;
    f0 = v.x; f1 = v.y; f2 = v.z; f3 = v.w;
  } else {
    const unsigned short* xr = (const unsigned short*)xv + (size_t)row * CC + lane * 4;
    uint2 v = *(const uint2*)xr;
    f0 = bf2f(v.x & 0xffffu); f1 = bf2f(v.x >> 16);
    f2 = bf2f(v.y & 0xffffu); f3 = bf2f(v.y >> 16);
  }
  float s = f0 + f1 + f2 + f3;
  float s2 = f0 * f0 + f1 * f1 + f2 * f2 + f3 * f3;
#pragma unroll
  for (int off = 32; off >= 1; off >>= 1) {
    s += __shfl_xor(s, off);
    s2 += __shfl_xor(s2, off);
  }
  if (lane == 0) {
    float mu = s * (1.0f / CC);
    float var = s2 * (1.0f / CC) - mu * mu;
    stats[row] = make_float2(mu, rsqrtf(var + 1e-5f));
  }
}

// ---------------- K2: fused LN + ALL THREE projections in one launch --------
__global__ __launch_bounds__(256) void qkv3_kernel(
    const void* __restrict__ xv, const float2* __restrict__ stats,
    const unsigned short* __restrict__ gmb, const unsigned short* __restrict__ btb,
    const unsigned short* __restrict__ Wq, const unsigned short* __restrict__ Wk,
    const unsigned short* __restrict__ Wv, const unsigned short* __restrict__ bq,
    const unsigned short* __restrict__ bk, const unsigned short* __restrict__ bv,
    unsigned short* __restrict__ oq, unsigned short* __restrict__ ok,
    unsigned short* __restrict__ ov, int row0, const int* __restrict__ flagp) {
  constexpr int LD = 56;
  alignas(16) __shared__ unsigned short As[128 * LD];
  alignas(16) __shared__ unsigned short Bs[128 * LD];
  __shared__ float gf[CC], bfv[CC];
  int tid = threadIdx.x;
  int flag = *flagp;
  gf[tid] = bf2f(gmb[tid]);
  bfv[tid] = bf2f(btb[tid]);
  int w = blockIdx.y >> 1;
  const unsigned short* Wb = (w == 0) ? Wq : (w == 1) ? Wk : Wv;
  const unsigned short* biasb = (w == 0) ? bq : (w == 1) ? bk : bv;
  unsigned short* outp = (w == 0) ? oq : (w == 1) ? ok : ov;
  int transposed = (w == 2);
  int row0e = row0 + blockIdx.z * TT;
  unsigned short* outpe = outp + (size_t)blockIdx.z * TT * CC;
  int m0 = blockIdx.x * 128, n0 = (blockIdx.y & 1) * 128;
  int wid = tid >> 6, lane = tid & 63, qd = lane >> 4, l15 = lane & 15;
  int wm = wid >> 1, wn = wid & 1;
  f32x4 acc[4][4] = {};
  int srow = tid >> 2, sc8 = (tid & 3) * 8;
  float2 st0 = stats[row0e + m0 + srow];
  float2 st1 = stats[row0e + m0 + srow + 64];
  for (int kk = 0; kk < 8; kk++) {
    int k0 = kk * 32;
    __syncthreads();
#pragma unroll
    for (int rr = 0; rr < 2; rr++) {
      int r = srow + rr * 64;
      float2 st = rr ? st1 : st0;
      float v[8];
      if (flag) {
        const float* xr = (const float*)xv + (size_t)(row0e + m0 + r) * CC + k0 + sc8;
        float4 a = *(const float4*)xr;
        float4 b2 = *(const float4*)(xr + 4);
        v[0] = a.x; v[1] = a.y; v[2] = a.z; v[3] = a.w;
        v[4] = b2.x; v[5] = b2.y; v[6] = b2.z; v[7] = b2.w;
      } else {
        uint4 u = *(const uint4*)((const unsigned short*)xv +
                                  (size_t)(row0e + m0 + r) * CC + k0 + sc8);
        v[0] = bf2f(u.x & 0xffffu); v[1] = bf2f(u.x >> 16);
        v[2] = bf2f(u.y & 0xffffu); v[3] = bf2f(u.y >> 16);
        v[4] = bf2f(u.z & 0xffffu); v[5] = bf2f(u.z >> 16);
        v[6] = bf2f(u.w & 0xffffu); v[7] = bf2f(u.w >> 16);
      }
      union { unsigned short s[8]; uint4 u; } o;
#pragma unroll
      for (int j = 0; j < 8; j++)
        o.s[j] = f2bf((v[j] - st.x) * st.y * gf[k0 + sc8 + j] + bfv[k0 + sc8 + j]);
      *(uint4*)&As[r * LD + sc8] = o.u;
    }
    *(uint4*)&Bs[srow * LD + sc8] =
        *(const uint4*)(Wb + (size_t)(n0 + srow) * CC + k0 + sc8);
    *(uint4*)&Bs[(srow + 64) * LD + sc8] =
        *(const uint4*)(Wb + (size_t)(n0 + srow + 64) * CC + k0 + sc8);
    __syncthreads();
    short8 a[4], bfr[4];
#pragma unroll
    for (int mi = 0; mi < 4; mi++)
      a[mi] = *(const short8*)&As[(wm * 64 + mi * 16 + l15) * LD + qd * 8];
#pragma unroll
    for (int ni = 0; ni < 4; ni++)
      bfr[ni] = *(const short8*)&Bs[(wn * 64 + ni * 16 + l15) * LD + qd * 8];
#pragma unroll
    for (int mi = 0; mi < 4; mi++)
#pragma unroll
      for (int ni = 0; ni < 4; ni++)
        acc[mi][ni] =
            __builtin_amdgcn_mfma_f32_16x16x32_bf16(a[mi], bfr[ni], acc[mi][ni], 0, 0, 0);
  }
#pragma unroll
  for (int mi = 0; mi < 4; mi++)
#pragma unroll
    for (int ni = 0; ni < 4; ni++) {
      int n = n0 + wn * 64 + ni * 16 + l15;
      float bsv = bf2f(biasb[n]);
#pragma unroll
      for (int r = 0; r < 4; r++) {
        int m = m0 + wm * 64 + mi * 16 + qd * 4 + r;
        unsigned short val = f2bf(acc[mi][ni][r] + bsv);
        if (transposed)
          outpe[(size_t)n * TT + m] = val;
        else
          outpe[(size_t)m * CC + n] = val;
      }
    }
}

// ---------------- K3: zsum v5 — 512 threads (8 waves), TLP latency hiding ----
// t-tile 32/block; wave handles s-slab 16 per 128-s chunk.
__global__ __launch_bounds__(512, 4) void zsum_kernel(
    const unsigned short* __restrict__ q, const unsigned short* __restrict__ k,
    float* __restrict__ zinvp, int swiz) {
  __shared__ float Zp[8][32];
  int bx = blockIdx.x;
  int batch = swiz ? ((bx & 7) >> 1) : 0;
  int tile = swiz ? ((bx >> 3) * 2 + (bx & 1)) : bx;
  const unsigned short* qb = q + (size_t)batch * TT * CC;
  const unsigned short* kb = k + (size_t)batch * TT * CC;
  float* zinv = zinvp + (size_t)batch * TT;
  int tid = threadIdx.x, wid = tid >> 6, lane = tid & 63, qd = lane >> 4, l15 = lane & 15;
  int t0 = tile * 32;
  short8 afix[2][8];  // Q[t-tile] fixed A operand
#pragma unroll
  for (int mi = 0; mi < 2; mi++)
#pragma unroll
    for (int kk = 0; kk < 8; kk++)
      afix[mi][kk] =
          *(const short8*)(qb + (size_t)(t0 + mi * 16 + l15) * CC + kk * 32 + qd * 8);
  float zacc[2][4] = {};
  const unsigned short* kbase = kb + (size_t)(wid * 16 + l15) * CC + qd * 8;
  for (int sc = 0; sc < TT; sc += 128) {
    f32x4 sacc[2] = {};
#pragma unroll
    for (int kk = 0; kk < 8; kk++) {
      short8 b0 = *(const short8*)(kbase + (size_t)sc * CC + kk * 32);
      sacc[0] = __builtin_amdgcn_mfma_f32_16x16x32_bf16(afix[0][kk], b0, sacc[0], 0, 0, 0);
      sacc[1] = __builtin_amdgcn_mfma_f32_16x16x32_bf16(afix[1][kk], b0, sacc[1], 0, 0, 0);
    }
#pragma unroll
    for (int mi = 0; mi < 2; mi++)
#pragma unroll
      for (int r = 0; r < 4; r++)
        zacc[mi][r] += __expf(fminf(sacc[mi][r] * SCALE, ECLAMP));
  }
#pragma unroll
  for (int mi = 0; mi < 2; mi++)
#pragma unroll
    for (int r = 0; r < 4; r++) {
      float z = zacc[mi][r];
      z += __shfl_xor(z, 1); z += __shfl_xor(z, 2);
      z += __shfl_xor(z, 4); z += __shfl_xor(z, 8);
      zacc[mi][r] = z;
    }
  if (l15 == 0) {
#pragma unroll
    for (int mi = 0; mi < 2; mi++)
#pragma unroll
      for (int r = 0; r < 4; r++) Zp[wid][mi * 16 + qd * 4 + r] = zacc[mi][r];
  }
  __syncthreads();
  if (tid < 32) {
    float Z = 0.0f;
#pragma unroll
    for (int w = 0; w < 8; w++) Z += Zp[w][tid];
    zinv[t0 + tid] = 1.0f / Z;
  }
}

// ---------------- K4: attn v5 — 512 threads (8 waves), TLP latency hiding ----
// s-tile 32/block; S-phase wave t-slab 16; PV wave c-slab 32.
__global__ __launch_bounds__(512, 4) void attn_kernel(
    const unsigned short* __restrict__ q, const unsigned short* __restrict__ k,
    const unsigned short* __restrict__ vt, const float* __restrict__ zinvp,
    const void* __restrict__ xv, float* __restrict__ out, int swiz, int row0,
    const int* __restrict__ flagp) {
  constexpr int LPt = 136;  // 272 B row stride
  alignas(16) __shared__ unsigned short Pt[2][32 * LPt];  // double-buffered, 17.4 KB
  int bx = blockIdx.x;
  int batch = swiz ? ((bx & 7) >> 1) : 0;
  int tile = swiz ? ((bx >> 3) * 2 + (bx & 1)) : bx;
  int flag = *flagp;
  const unsigned short* qb = q + (size_t)batch * TT * CC;
  const unsigned short* kb = k + (size_t)batch * TT * CC;
  const unsigned short* vtb = vt + (size_t)batch * TT * CC;  // [c][t]
  const float* zinv = zinvp + (size_t)batch * TT;
  int row0e = swiz ? batch * TT : row0;
  int tid = threadIdx.x, wid = tid >> 6, lane = tid & 63, qd = lane >> 4, l15 = lane & 15;
  int s0 = tile * 32;
  short8 afix[2][8];  // K[s-tile] fixed A operand
#pragma unroll
  for (int mi = 0; mi < 2; mi++)
#pragma unroll
    for (int kk = 0; kk < 8; kk++)
      afix[mi][kk] =
          *(const short8*)(kb + (size_t)(s0 + mi * 16 + l15) * CC + kk * 32 + qd * 8);
  f32x4 oacc[2][2] = {};
  const unsigned short* qrow = qb + (size_t)(wid * 16 + l15) * CC + qd * 8;  // t-slab 16
  const unsigned short* vrow[2];
#pragma unroll
  for (int ni = 0; ni < 2; ni++)
    vrow[ni] = vtb + (size_t)(wid * 32 + ni * 16 + l15) * TT + qd * 8;  // c-slab 32
  for (int tc = 0; tc < TT; tc += 128) {
    int buf = (tc >> 7) & 1;
    // ---- S^T phase: A=K (m=s), B=Q (n=t); this wave covers t = tc+wid*16+[0,16)
    f32x4 sacc[2] = {};
#pragma unroll
    for (int kk = 0; kk < 8; kk++) {
      short8 b0 = *(const short8*)(qrow + (size_t)tc * CC + kk * 32);
      sacc[0] = __builtin_amdgcn_mfma_f32_16x16x32_bf16(afix[0][kk], b0, sacc[0], 0, 0, 0);
      sacc[1] = __builtin_amdgcn_mfma_f32_16x16x32_bf16(afix[1][kk], b0, sacc[1], 0, 0, 0);
    }
    // ---- exp + P^T -> LDS (row = s_local, col = t_local) ----
    float zz = zinv[tc + wid * 16 + l15];
    int t_loc = wid * 16 + l15;
#pragma unroll
    for (int mi = 0; mi < 2; mi++)
#pragma unroll
      for (int r = 0; r < 4; r++) {
        float p = __expf(fminf(sacc[mi][r] * SCALE, ECLAMP)) * zz;
        Pt[buf][(mi * 16 + qd * 4 + r) * LPt + t_loc] = f2bf(p);
      }
    __syncthreads();
    // ---- PV phase: oacc[s, c-slab 32] += P^T[s,t] * Vt[c,t] ----
#pragma unroll
    for (int kt = 0; kt < 4; kt++) {
      short8 a0 = *(const short8*)&Pt[buf][l15 * LPt + kt * 32 + qd * 8];
      short8 a1 = *(const short8*)&Pt[buf][(16 + l15) * LPt + kt * 32 + qd * 8];
#pragma unroll
      for (int ni = 0; ni < 2; ni++) {
        short8 b = *(const short8*)(vrow[ni] + tc + kt * 32);
        oacc[0][ni] = __builtin_amdgcn_mfma_f32_16x16x32_bf16(a0, b, oacc[0][ni], 0, 0, 0);
        oacc[1][ni] = __builtin_amdgcn_mfma_f32_16x16x32_bf16(a1, b, oacc[1][ni], 0, 0, 0);
      }
    }
  }
  // epilogue: out(f32) = oacc + x
#pragma unroll
  for (int mi = 0; mi < 2; mi++)
#pragma unroll
    for (int ni = 0; ni < 2; ni++)
#pragma unroll
      for (int r = 0; r < 4; r++) {
        int s = s0 + mi * 16 + qd * 4 + r;
        int c = wid * 32 + ni * 16 + l15;
        size_t idx = ((size_t)(row0e + s)) * CC + c;
        float xr = flag ? ((const float*)xv)[idx] : bf2f(((const unsigned short*)xv)[idx]);
        out[idx] = oacc[mi][ni][r] + xr;
      }
}

extern "C" void kernel_launch(void* const* d_in, const int* in_sizes, int n_in,
                              void* d_out, int out_size, void* d_ws, size_t ws_size,
                              hipStream_t stream) {
  const void* x = d_in[0];
  const void* gamma = d_in[1];
  const void* beta = d_in[2];
  const void* Wq = d_in[3];
  const void* bq = d_in[4];
  const void* Wk = d_in[5];
  const void* bk = d_in[6];
  const void* Wv = d_in[7];
  const void* bv = d_in[8];
  float* out = (float*)d_out;  // reference output dtype: float32

  char* ws = (char*)d_ws;
  int* flag = (int*)(ws + 0);
  float2* stats = (float2*)(ws + 1024);                      // 128 KiB
  unsigned short* gmb = (unsigned short*)(ws + 132096);
  unsigned short* btb = (unsigned short*)(ws + 132608);
  unsigned short* bqb = (unsigned short*)(ws + 133120);
  unsigned short* bkb = (unsigned short*)(ws + 133632);
  unsigned short* bvb = (unsigned short*)(ws + 134144);
  unsigned short* Wqb = (unsigned short*)(ws + 135168);      // 128 KiB each
  unsigned short* Wkb = (unsigned short*)(ws + 266240);
  unsigned short* Wvb = (unsigned short*)(ws + 397312);
  float* zinv = (float*)(ws + 593920);                       // 64 KiB
  unsigned short* qb = (unsigned short*)(ws + 1048576);
  const int full = (ws_size >= 26214400u);
  size_t qkv_bytes = full ? 8388608u : 2097152u;
  unsigned short* kb = (unsigned short*)((char*)qb + qkv_bytes);
  unsigned short* vtb = (unsigned short*)((char*)kb + qkv_bytes);  // V^T [b][c][t]

  detect_kernel<<<dim3(1), dim3(256), 0, stream>>>((const unsigned short*)x, flag);
  cvt_all_kernel<<<dim3(773), dim3(256), 0, stream>>>(Wq, Wk, Wv, bq, bk, bv, gamma, beta,
                                                      Wqb, Wkb, Wvb, bqb, bkb, bvb, gmb,
                                                      btb, flag);
  stats_kernel<<<dim3(BB * TT / 4), dim3(256), 0, stream>>>(x, stats, flag);

  if (full) {
    qkv3_kernel<<<dim3(32, 6, BB), dim3(256), 0, stream>>>(
        x, stats, gmb, btb, Wqb, Wkb, Wvb, bqb, bkb, bvb, qb, kb, vtb, 0, flag);
    zsum_kernel<<<dim3(512), dim3(512), 0, stream>>>(qb, kb, zinv, 1);
    attn_kernel<<<dim3(512), dim3(512), 0, stream>>>(qb, kb, vtb, zinv, x, out, 1, 0,
                                                     flag);
  } else {
    for (int b = 0; b < BB; b++) {
      int row0 = b * TT;
      qkv3_kernel<<<dim3(32, 6, 1), dim3(256), 0, stream>>>(
          x, stats, gmb, btb, Wqb, Wkb, Wvb, bqb, bkb, bvb, qb, kb, vtb, row0, flag);
      zsum_kernel<<<dim3(128), dim3(512), 0, stream>>>(qb, kb, zinv, 0);
      attn_kernel<<<dim3(128), dim3(512), 0, stream>>>(qb, kb, vtb, zinv, x, out, 0, row0,
                                                       flag);
    }
  }
}

// Round 11
// 348.211 us; speedup vs baseline: 5.9957x; 1.4177x over previous
//
#include <hip/hip_runtime.h>

#define BB 4
#define TT 4096
#define CC 256

typedef __attribute__((ext_vector_type(8))) short short8;   // 8 x bf16 (4 VGPRs)
typedef __attribute__((ext_vector_type(4))) float f32x4;

#define SCALE 0.0625f  // C^-0.5 = 1/16
#define ECLAMP 60.0f   // exp-arg clamp, identical in zsum & attn

__device__ __forceinline__ float bf2f(unsigned short u) {
  union { unsigned int i; float f; } v; v.i = ((unsigned int)u) << 16; return v.f;
}
__device__ __forceinline__ unsigned short f2bf(float f) {
  union { float f; unsigned int i; } v; v.f = f;
  unsigned int x = v.i;
  unsigned int r = x + 0x7fffu + ((x >> 16) & 1u);  // RNE
  return (unsigned short)(r >> 16);
}

// ---------------- K0: input dtype detection ----------------
__global__ __launch_bounds__(256) void detect_kernel(const unsigned short* __restrict__ xu,
                                                     int* __restrict__ flag) {
  __shared__ int part[4];
  int tid = threadIdx.x;
  int cnt = 0;
#pragma unroll
  for (int i = 0; i < 32; i++) {
    unsigned short u = xu[tid * 32 + i];
    int e = (u >> 7) & 0xff;
    cnt += (e >= 0xC0) ? 1 : 0;
  }
#pragma unroll
  for (int off = 32; off >= 1; off >>= 1) cnt += __shfl_xor(cnt, off);
  if ((tid & 63) == 0) part[tid >> 6] = cnt;
  __syncthreads();
  if (tid == 0) flag[0] = (part[0] + part[1] + part[2] + part[3] > 64) ? 1 : 0;
}

// ---------------- K0b: ALL dtype conversions in ONE launch ----------------
__global__ __launch_bounds__(256) void cvt_all_kernel(
    const void* __restrict__ Wq, const void* __restrict__ Wk, const void* __restrict__ Wv,
    const void* __restrict__ bq, const void* __restrict__ bk, const void* __restrict__ bv,
    const void* __restrict__ gm, const void* __restrict__ bt,
    unsigned short* __restrict__ Wqb, unsigned short* __restrict__ Wkb,
    unsigned short* __restrict__ Wvb, unsigned short* __restrict__ bqb,
    unsigned short* __restrict__ bkb, unsigned short* __restrict__ bvb,
    unsigned short* __restrict__ gmb, unsigned short* __restrict__ btb,
    const int* __restrict__ flagp) {
  int bx = blockIdx.x, tid = threadIdx.x;
  const void* src;
  unsigned short* dst;
  int idx;
  if (bx < 256) { src = Wq; dst = Wqb; idx = bx * 256 + tid; }
  else if (bx < 512) { src = Wk; dst = Wkb; idx = (bx - 256) * 256 + tid; }
  else if (bx < 768) { src = Wv; dst = Wvb; idx = (bx - 512) * 256 + tid; }
  else {
    int w = bx - 768; idx = tid;
    src = (w == 0) ? bq : (w == 1) ? bk : (w == 2) ? bv : (w == 3) ? gm : bt;
    dst = (w == 0) ? bqb : (w == 1) ? bkb : (w == 2) ? bvb : (w == 3) ? gmb : btb;
  }
  dst[idx] = (*flagp) ? f2bf(((const float*)src)[idx]) : ((const unsigned short*)src)[idx];
}

// ---------------- K1: LayerNorm row stats (mu, rsqrt(var+eps)) ----------------
__global__ __launch_bounds__(256) void stats_kernel(const void* __restrict__ xv,
                                                    float2* __restrict__ stats,
                                                    const int* __restrict__ flagp) {
  int row = blockIdx.x * 4 + (threadIdx.x >> 6);
  int lane = threadIdx.x & 63;
  float f0, f1, f2, f3;
  if (*flagp) {
    const float* xr = (const float*)xv + (size_t)row * CC + lane * 4;
    float4 v = *(const float4*)xr;
    f0 = v.x; f1 = v.y; f2 = v.z; f3 = v.w;
  } else {
    const unsigned short* xr = (const unsigned short*)xv + (size_t)row * CC + lane * 4;
    uint2 v = *(const uint2*)xr;
    f0 = bf2f(v.x & 0xffffu); f1 = bf2f(v.x >> 16);
    f2 = bf2f(v.y & 0xffffu); f3 = bf2f(v.y >> 16);
  }
  float s = f0 + f1 + f2 + f3;
  float s2 = f0 * f0 + f1 * f1 + f2 * f2 + f3 * f3;
#pragma unroll
  for (int off = 32; off >= 1; off >>= 1) {
    s += __shfl_xor(s, off);
    s2 += __shfl_xor(s2, off);
  }
  if (lane == 0) {
    float mu = s * (1.0f / CC);
    float var = s2 * (1.0f / CC) - mu * mu;
    stats[row] = make_float2(mu, rsqrtf(var + 1e-5f));
  }
}

// ---------------- K2: fused LN + ALL THREE projections in one launch --------
__global__ __launch_bounds__(256) void qkv3_kernel(
    const void* __restrict__ xv, const float2* __restrict__ stats,
    const unsigned short* __restrict__ gmb, const unsigned short* __restrict__ btb,
    const unsigned short* __restrict__ Wq, const unsigned short* __restrict__ Wk,
    const unsigned short* __restrict__ Wv, const unsigned short* __restrict__ bq,
    const unsigned short* __restrict__ bk, const unsigned short* __restrict__ bv,
    unsigned short* __restrict__ oq, unsigned short* __restrict__ ok,
    unsigned short* __restrict__ ov, int row0, const int* __restrict__ flagp) {
  constexpr int LD = 56;
  alignas(16) __shared__ unsigned short As[128 * LD];
  alignas(16) __shared__ unsigned short Bs[128 * LD];
  __shared__ float gf[CC], bfv[CC];
  int tid = threadIdx.x;
  int flag = *flagp;
  gf[tid] = bf2f(gmb[tid]);
  bfv[tid] = bf2f(btb[tid]);
  int w = blockIdx.y >> 1;
  const unsigned short* Wb = (w == 0) ? Wq : (w == 1) ? Wk : Wv;
  const unsigned short* biasb = (w == 0) ? bq : (w == 1) ? bk : bv;
  unsigned short* outp = (w == 0) ? oq : (w == 1) ? ok : ov;
  int transposed = (w == 2);
  int row0e = row0 + blockIdx.z * TT;
  unsigned short* outpe = outp + (size_t)blockIdx.z * TT * CC;
  int m0 = blockIdx.x * 128, n0 = (blockIdx.y & 1) * 128;
  int wid = tid >> 6, lane = tid & 63, qd = lane >> 4, l15 = lane & 15;
  int wm = wid >> 1, wn = wid & 1;
  f32x4 acc[4][4] = {};
  int srow = tid >> 2, sc8 = (tid & 3) * 8;
  float2 st0 = stats[row0e + m0 + srow];
  float2 st1 = stats[row0e + m0 + srow + 64];
  for (int kk = 0; kk < 8; kk++) {
    int k0 = kk * 32;
    __syncthreads();
#pragma unroll
    for (int rr = 0; rr < 2; rr++) {
      int r = srow + rr * 64;
      float2 st = rr ? st1 : st0;
      float v[8];
      if (flag) {
        const float* xr = (const float*)xv + (size_t)(row0e + m0 + r) * CC + k0 + sc8;
        float4 a = *(const float4*)xr;
        float4 b2 = *(const float4*)(xr + 4);
        v[0] = a.x; v[1] = a.y; v[2] = a.z; v[3] = a.w;
        v[4] = b2.x; v[5] = b2.y; v[6] = b2.z; v[7] = b2.w;
      } else {
        uint4 u = *(const uint4*)((const unsigned short*)xv +
                                  (size_t)(row0e + m0 + r) * CC + k0 + sc8);
        v[0] = bf2f(u.x & 0xffffu); v[1] = bf2f(u.x >> 16);
        v[2] = bf2f(u.y & 0xffffu); v[3] = bf2f(u.y >> 16);
        v[4] = bf2f(u.z & 0xffffu); v[5] = bf2f(u.z >> 16);
        v[6] = bf2f(u.w & 0xffffu); v[7] = bf2f(u.w >> 16);
      }
      union { unsigned short s[8]; uint4 u; } o;
#pragma unroll
      for (int j = 0; j < 8; j++)
        o.s[j] = f2bf((v[j] - st.x) * st.y * gf[k0 + sc8 + j] + bfv[k0 + sc8 + j]);
      *(uint4*)&As[r * LD + sc8] = o.u;
    }
    *(uint4*)&Bs[srow * LD + sc8] =
        *(const uint4*)(Wb + (size_t)(n0 + srow) * CC + k0 + sc8);
    *(uint4*)&Bs[(srow + 64) * LD + sc8] =
        *(const uint4*)(Wb + (size_t)(n0 + srow + 64) * CC + k0 + sc8);
    __syncthreads();
    short8 a[4], bfr[4];
#pragma unroll
    for (int mi = 0; mi < 4; mi++)
      a[mi] = *(const short8*)&As[(wm * 64 + mi * 16 + l15) * LD + qd * 8];
#pragma unroll
    for (int ni = 0; ni < 4; ni++)
      bfr[ni] = *(const short8*)&Bs[(wn * 64 + ni * 16 + l15) * LD + qd * 8];
#pragma unroll
    for (int mi = 0; mi < 4; mi++)
#pragma unroll
      for (int ni = 0; ni < 4; ni++)
        acc[mi][ni] =
            __builtin_amdgcn_mfma_f32_16x16x32_bf16(a[mi], bfr[ni], acc[mi][ni], 0, 0, 0);
  }
#pragma unroll
  for (int mi = 0; mi < 4; mi++)
#pragma unroll
    for (int ni = 0; ni < 4; ni++) {
      int n = n0 + wn * 64 + ni * 16 + l15;
      float bsv = bf2f(biasb[n]);
#pragma unroll
      for (int r = 0; r < 4; r++) {
        int m = m0 + wm * 64 + mi * 16 + qd * 4 + r;
        unsigned short val = f2bf(acc[mi][ni][r] + bsv);
        if (transposed)
          outpe[(size_t)n * TT + m] = val;
        else
          outpe[(size_t)m * CC + n] = val;
      }
    }
}

// ---------------- K3: zsum v6 — t-tile 64, 1 block/CU, halved L2 traffic ----
__global__ __launch_bounds__(512, 2) void zsum_kernel(
    const unsigned short* __restrict__ q, const unsigned short* __restrict__ k,
    float* __restrict__ zinvp, int swiz) {
  __shared__ float Zp[8][64];
  int bx = blockIdx.x;
  int batch = swiz ? ((bx & 7) >> 1) : 0;
  int tile = swiz ? ((bx >> 3) * 2 + (bx & 1)) : bx;  // [0,64)
  const unsigned short* qb = q + (size_t)batch * TT * CC;
  const unsigned short* kb = k + (size_t)batch * TT * CC;
  float* zinv = zinvp + (size_t)batch * TT;
  int tid = threadIdx.x, wid = tid >> 6, lane = tid & 63, qd = lane >> 4, l15 = lane & 15;
  int t0 = tile * 64;
  short8 afix[4][8];  // Q[t-tile 64] fixed A operand
#pragma unroll
  for (int mi = 0; mi < 4; mi++)
#pragma unroll
    for (int kk = 0; kk < 8; kk++)
      afix[mi][kk] =
          *(const short8*)(qb + (size_t)(t0 + mi * 16 + l15) * CC + kk * 32 + qd * 8);
  float zacc[4][4] = {};
  const unsigned short* kbase = kb + (size_t)(wid * 16 + l15) * CC + qd * 8;
  for (int sc = 0; sc < TT; sc += 128) {
    f32x4 sacc[4] = {};
#pragma unroll
    for (int kk = 0; kk < 8; kk++) {
      short8 b0 = *(const short8*)(kbase + (size_t)sc * CC + kk * 32);
#pragma unroll
      for (int mi = 0; mi < 4; mi++)
        sacc[mi] = __builtin_amdgcn_mfma_f32_16x16x32_bf16(afix[mi][kk], b0, sacc[mi], 0, 0, 0);
    }
#pragma unroll
    for (int mi = 0; mi < 4; mi++)
#pragma unroll
      for (int r = 0; r < 4; r++)
        zacc[mi][r] += __expf(fminf(sacc[mi][r] * SCALE, ECLAMP));
  }
#pragma unroll
  for (int mi = 0; mi < 4; mi++)
#pragma unroll
    for (int r = 0; r < 4; r++) {
      float z = zacc[mi][r];
      z += __shfl_xor(z, 1); z += __shfl_xor(z, 2);
      z += __shfl_xor(z, 4); z += __shfl_xor(z, 8);
      zacc[mi][r] = z;
    }
  if (l15 == 0) {
#pragma unroll
    for (int mi = 0; mi < 4; mi++)
#pragma unroll
      for (int r = 0; r < 4; r++) Zp[wid][mi * 16 + qd * 4 + r] = zacc[mi][r];
  }
  __syncthreads();
  if (tid < 64) {
    float Z = 0.0f;
#pragma unroll
    for (int w = 0; w < 8; w++) Z += Zp[w][tid];
    zinv[t0 + tid] = 1.0f / Z;
  }
}

// ---------------- K4: attn v6 — s-tile 64, 1 block/CU, halved L2 traffic ----
// out[s,c] = x[s,c] + sum_t P[t,s]*v[t,c]; S^T: A=K[s-tile 64] regs, B=Q direct.
__global__ __launch_bounds__(512, 2) void attn_kernel(
    const unsigned short* __restrict__ q, const unsigned short* __restrict__ k,
    const unsigned short* __restrict__ vt, const float* __restrict__ zinvp,
    const void* __restrict__ xv, float* __restrict__ out, int swiz, int row0,
    const int* __restrict__ flagp) {
  constexpr int LPt = 136;  // 272 B row stride
  alignas(16) __shared__ unsigned short Pt[2][64 * LPt];  // double-buffered, 34.8 KB
  int bx = blockIdx.x;
  int batch = swiz ? ((bx & 7) >> 1) : 0;
  int tile = swiz ? ((bx >> 3) * 2 + (bx & 1)) : bx;  // [0,64)
  int flag = *flagp;
  const unsigned short* qb = q + (size_t)batch * TT * CC;
  const unsigned short* kb = k + (size_t)batch * TT * CC;
  const unsigned short* vtb = vt + (size_t)batch * TT * CC;  // [c][t]
  const float* zinv = zinvp + (size_t)batch * TT;
  int row0e = swiz ? batch * TT : row0;
  int tid = threadIdx.x, wid = tid >> 6, lane = tid & 63, qd = lane >> 4, l15 = lane & 15;
  int s0 = tile * 64;
  short8 afix[4][8];  // K[s-tile 64] fixed A operand
#pragma unroll
  for (int mi = 0; mi < 4; mi++)
#pragma unroll
    for (int kk = 0; kk < 8; kk++)
      afix[mi][kk] =
          *(const short8*)(kb + (size_t)(s0 + mi * 16 + l15) * CC + kk * 32 + qd * 8);
  f32x4 oacc[4][2] = {};
  const unsigned short* qrow = qb + (size_t)(wid * 16 + l15) * CC + qd * 8;  // t-slab 16
  const unsigned short* vrow[2];
#pragma unroll
  for (int ni = 0; ni < 2; ni++)
    vrow[ni] = vtb + (size_t)(wid * 32 + ni * 16 + l15) * TT + qd * 8;  // c-slab 32
  for (int tc = 0; tc < TT; tc += 128) {
    int buf = (tc >> 7) & 1;
    // ---- S^T phase: A=K (m=s, 64), B=Q (n=t); wave covers t = tc+wid*16+[0,16)
    f32x4 sacc[4] = {};
#pragma unroll
    for (int kk = 0; kk < 8; kk++) {
      short8 b0 = *(const short8*)(qrow + (size_t)tc * CC + kk * 32);
#pragma unroll
      for (int mi = 0; mi < 4; mi++)
        sacc[mi] = __builtin_amdgcn_mfma_f32_16x16x32_bf16(afix[mi][kk], b0, sacc[mi], 0, 0, 0);
    }
    // ---- exp + P^T -> LDS (row = s_local, col = t_local) ----
    float zz = zinv[tc + wid * 16 + l15];
    int t_loc = wid * 16 + l15;
#pragma unroll
    for (int mi = 0; mi < 4; mi++)
#pragma unroll
      for (int r = 0; r < 4; r++) {
        float p = __expf(fminf(sacc[mi][r] * SCALE, ECLAMP)) * zz;
        Pt[buf][(mi * 16 + qd * 4 + r) * LPt + t_loc] = f2bf(p);
      }
    __syncthreads();
    // ---- PV phase: oacc[s 64, c-slab 32] += P^T[s,t] * Vt[c,t] ----
#pragma unroll
    for (int kt = 0; kt < 4; kt++) {
      short8 a[4];
#pragma unroll
      for (int mi = 0; mi < 4; mi++)
        a[mi] = *(const short8*)&Pt[buf][(mi * 16 + l15) * LPt + kt * 32 + qd * 8];
#pragma unroll
      for (int ni = 0; ni < 2; ni++) {
        short8 b = *(const short8*)(vrow[ni] + tc + kt * 32);
#pragma unroll
        for (int mi = 0; mi < 4; mi++)
          oacc[mi][ni] = __builtin_amdgcn_mfma_f32_16x16x32_bf16(a[mi], b, oacc[mi][ni], 0, 0, 0);
      }
    }
  }
  // epilogue: out(f32) = oacc + x
#pragma unroll
  for (int mi = 0; mi < 4; mi++)
#pragma unroll
    for (int ni = 0; ni < 2; ni++)
#pragma unroll
      for (int r = 0; r < 4; r++) {
        int s = s0 + mi * 16 + qd * 4 + r;
        int c = wid * 32 + ni * 16 + l15;
        size_t idx = ((size_t)(row0e + s)) * CC + c;
        float xr = flag ? ((const float*)xv)[idx] : bf2f(((const unsigned short*)xv)[idx]);
        out[idx] = oacc[mi][ni][r] + xr;
      }
}

extern "C" void kernel_launch(void* const* d_in, const int* in_sizes, int n_in,
                              void* d_out, int out_size, void* d_ws, size_t ws_size,
                              hipStream_t stream) {
  const void* x = d_in[0];
  const void* gamma = d_in[1];
  const void* beta = d_in[2];
  const void* Wq = d_in[3];
  const void* bq = d_in[4];
  const void* Wk = d_in[5];
  const void* bk = d_in[6];
  const void* Wv = d_in[7];
  const void* bv = d_in[8];
  float* out = (float*)d_out;  // reference output dtype: float32

  char* ws = (char*)d_ws;
  int* flag = (int*)(ws + 0);
  float2* stats = (float2*)(ws + 1024);                      // 128 KiB
  unsigned short* gmb = (unsigned short*)(ws + 132096);
  unsigned short* btb = (unsigned short*)(ws + 132608);
  unsigned short* bqb = (unsigned short*)(ws + 133120);
  unsigned short* bkb = (unsigned short*)(ws + 133632);
  unsigned short* bvb = (unsigned short*)(ws + 134144);
  unsigned short* Wqb = (unsigned short*)(ws + 135168);      // 128 KiB each
  unsigned short* Wkb = (unsigned short*)(ws + 266240);
  unsigned short* Wvb = (unsigned short*)(ws + 397312);
  float* zinv = (float*)(ws + 593920);                       // 64 KiB
  unsigned short* qb = (unsigned short*)(ws + 1048576);
  const int full = (ws_size >= 26214400u);
  size_t qkv_bytes = full ? 8388608u : 2097152u;
  unsigned short* kb = (unsigned short*)((char*)qb + qkv_bytes);
  unsigned short* vtb = (unsigned short*)((char*)kb + qkv_bytes);  // V^T [b][c][t]

  detect_kernel<<<dim3(1), dim3(256), 0, stream>>>((const unsigned short*)x, flag);
  cvt_all_kernel<<<dim3(773), dim3(256), 0, stream>>>(Wq, Wk, Wv, bq, bk, bv, gamma, beta,
                                                      Wqb, Wkb, Wvb, bqb, bkb, bvb, gmb,
                                                      btb, flag);
  stats_kernel<<<dim3(BB * TT / 4), dim3(256), 0, stream>>>(x, stats, flag);

  if (full) {
    qkv3_kernel<<<dim3(32, 6, BB), dim3(256), 0, stream>>>(
        x, stats, gmb, btb, Wqb, Wkb, Wvb, bqb, bkb, bvb, qb, kb, vtb, 0, flag);
    zsum_kernel<<<dim3(256), dim3(512), 0, stream>>>(qb, kb, zinv, 1);
    attn_kernel<<<dim3(256), dim3(512), 0, stream>>>(qb, kb, vtb, zinv, x, out, 1, 0,
                                                     flag);
  } else {
    for (int b = 0; b < BB; b++) {
      int row0 = b * TT;
      qkv3_kernel<<<dim3(32, 6, 1), dim3(256), 0, stream>>>(
          x, stats, gmb, btb, Wqb, Wkb, Wvb, bqb, bkb, bvb, qb, kb, vtb, row0, flag);
      zsum_kernel<<<dim3(64), dim3(512), 0, stream>>>(qb, kb, zinv, 0);
      attn_kernel<<<dim3(64), dim3(512), 0, stream>>>(qb, kb, vtb, zinv, x, out, 0, row0,
                                                      flag);
    }
  }
}